// Round 4
// baseline (329.781 us; speedup 1.0000x reference)
//
#include <hip/hip_runtime.h>

#define C_DIM 128
#define HW_DIM 6144

typedef __attribute__((ext_vector_type(8))) short short8;
typedef __attribute__((ext_vector_type(4))) float f32x4;

static __device__ __forceinline__ unsigned short f2bf(float x) {
    unsigned int u = __builtin_bit_cast(unsigned int, x);
    u = (u + 0x7FFFu + ((u >> 16) & 1u)) >> 16;
    return (unsigned short)u;
}
static __device__ __forceinline__ float bf2f(unsigned short u) {
    unsigned int x = ((unsigned int)u) << 16;
    return __builtin_bit_cast(float, x);
}
static __device__ __forceinline__ unsigned int pack2(float a, float b) {
    return (unsigned int)f2bf(a) | ((unsigned int)f2bf(b) << 16);
}
static __device__ __forceinline__ f32x4 mfma_bf16(short8 a, short8 b, f32x4 c) {
    return __builtin_amdgcn_mfma_f32_16x16x32_bf16(a, b, c, 0, 0, 0);
}
// async global->LDS, 16B per lane; LDS dest is wave-uniform-base + lane*16,
// global source is per-lane (pre-swizzled).
static __device__ __forceinline__ void gload16(const unsigned short* g,
                                               unsigned short* l) {
    __builtin_amdgcn_global_load_lds(
        (const __attribute__((address_space(1))) unsigned int*)g,
        (__attribute__((address_space(3))) unsigned int*)l, 16, 0, 0);
}
// Load one MFMA A-fragment (bf16) directly from global fp32 W[o][c]:
// lane (l16,quad) of row-tile base `o` needs W[o][c0 .. c0+7], c0=s*32+quad*8.
static __device__ __forceinline__ short8 wfrag(const float* Wrow) {
    float4 a = *(const float4*)Wrow;
    float4 b = *(const float4*)(Wrow + 4);
    unsigned int u[4] = {pack2(a.x, a.y), pack2(a.z, a.w),
                         pack2(b.x, b.y), pack2(b.z, b.w)};
    return *(const short8*)u;
}

// ---------------------------------------------------------------------------
// Fused (1x1 conv -> BN -> LReLU) x nconv kernel (r17, unchanged — passing).
// ---------------------------------------------------------------------------
struct MJob {
    const void* X;          // input
    const float* L;         // unused now
    const float* W1; const float* G1; const float* B1;
    const float* W2; const float* G2; const float* B2;
    void* out; const float* resid;
    float oscale; int in_mode; int out_mode; int nparts; int nconv;
};
struct MJobs { MJob j[3]; };

__global__ __launch_bounds__(256)
void conv_mfma(MJobs jobs)
{
    const MJob jb = (blockIdx.z == 0) ? jobs.j[0]
                  : (blockIdx.z == 1) ? jobs.j[1] : jobs.j[2];

    __shared__ __align__(16) unsigned short Xt[64 * 128];   // 16 KB conv1 B
    __shared__ __align__(16) unsigned short Ct[64 * 128];   // 16 KB mid / epi

    const int t    = threadIdx.x;
    const int b    = blockIdx.y;
    const int p0   = blockIdx.x * 64;
    const int wave = t >> 6;
    const int lane = t & 63;
    const int quad = lane >> 4;
    const int l16  = lane & 15;

    // ---- W fragments direct from global (rows o = (wave*2+mi)*16+l16) ----
    short8 af1[2][4], af2[2][4];
#pragma unroll
    for (int mi = 0; mi < 2; ++mi) {
        int o = (wave * 2 + mi) * 16 + l16;
#pragma unroll
        for (int s = 0; s < 4; ++s)
            af1[mi][s] = wfrag(jb.W1 + o * C_DIM + s * 32 + quad * 8);
    }
    if (jb.nconv == 2) {
#pragma unroll
        for (int mi = 0; mi < 2; ++mi) {
            int o = (wave * 2 + mi) * 16 + l16;
#pragma unroll
            for (int s = 0; s < 4; ++s)
                af2[mi][s] = wfrag(jb.W2 + o * C_DIM + s * 32 + quad * 8);
        }
    }

    // ---- stage X -> bf16 Xt[p][chunk^(p&15)] ----
    if (jb.in_mode == 0) {
        const float* Xg = (const float*)jb.X + (size_t)b * C_DIM * HW_DIM;
#pragma unroll
        for (int i = 0; i < 8; ++i) {
            int f = i * 1024 + t * 4;         // c = f>>6, p = f&63 (mult of 4)
            int c = f >> 6, p = f & 63;
            float4 x4 = *(const float4*)&Xg[(size_t)c * HW_DIM + p0 + p];
            float xv[4] = {x4.x, x4.y, x4.z, x4.w};
#pragma unroll
            for (int j = 0; j < 4; ++j) {
                int pp = p + j;
                Xt[pp * 128 + (((c >> 3) ^ (pp & 15)) * 8) + (c & 7)] = f2bf(xv[j]);
            }
        }
    } else {
        const unsigned short* Xg = (const unsigned short*)jb.X;
#pragma unroll
        for (int i = 0; i < 4; ++i) {
            int idx = t + 256 * i;            // p = idx>>4, ch = idx&15
            int p = idx >> 4, ch = idx & 15;
            uint4 v = *(const uint4*)&Xg[((size_t)b * HW_DIM + p0 + p) * C_DIM + ch * 8];
            *(uint4*)&Xt[p * 128 + ((ch ^ (p & 15)) * 8)] = v;
        }
    }
    __syncthreads();

    const float BNRS = 0.99999500003749972f;  // 1/sqrt(1 + 1e-5)

    // ---- conv1 GEMM ----
    f32x4 acc[2][4];
#pragma unroll
    for (int mi = 0; mi < 2; ++mi)
#pragma unroll
        for (int nt = 0; nt < 4; ++nt) acc[mi][nt] = (f32x4){0.f, 0.f, 0.f, 0.f};
#pragma unroll
    for (int nt = 0; nt < 4; ++nt)
#pragma unroll
        for (int s = 0; s < 4; ++s) {
            short8 bf = *(const short8*)
                &Xt[(nt * 16 + l16) * 128 + (((4 * s + quad) ^ l16) * 8)];
            acc[0][nt] = mfma_bf16(af1[0][s], bf, acc[0][nt]);
            acc[1][nt] = mfma_bf16(af1[1][s], bf, acc[1][nt]);
        }

    // ---- BN1 + LeakyReLU ----
#pragma unroll
    for (int mi = 0; mi < 2; ++mi)
#pragma unroll
        for (int r = 0; r < 4; ++r) {
            int o = (wave * 2 + mi) * 16 + quad * 4 + r;
            float sc = jb.G1[o] * BNRS, bb = jb.B1[o];
#pragma unroll
            for (int nt = 0; nt < 4; ++nt) {
                float y = fmaf(acc[mi][nt][r], sc, bb);
                acc[mi][nt][r] = y > 0.f ? y : 0.1f * y;
            }
        }

    if (jb.nconv == 2) {
        // ---- mid -> Ct in B-operand swizzle ----
#pragma unroll
        for (int mi = 0; mi < 2; ++mi)
#pragma unroll
            for (int nt = 0; nt < 4; ++nt)
#pragma unroll
                for (int r = 0; r < 4; ++r) {
                    int o = (wave * 2 + mi) * 16 + quad * 4 + r;
                    int p = nt * 16 + l16;
                    Ct[p * 128 + (((o >> 3) ^ (p & 15)) * 8) + (o & 7)] =
                        f2bf(acc[mi][nt][r]);
                }
        __syncthreads();

        // ---- conv2 GEMM from Ct ----
#pragma unroll
        for (int mi = 0; mi < 2; ++mi)
#pragma unroll
            for (int nt = 0; nt < 4; ++nt) acc[mi][nt] = (f32x4){0.f, 0.f, 0.f, 0.f};
#pragma unroll
        for (int nt = 0; nt < 4; ++nt)
#pragma unroll
            for (int s = 0; s < 4; ++s) {
                short8 bf = *(const short8*)
                    &Ct[(nt * 16 + l16) * 128 + (((4 * s + quad) ^ l16) * 8)];
                acc[0][nt] = mfma_bf16(af2[0][s], bf, acc[0][nt]);
                acc[1][nt] = mfma_bf16(af2[1][s], bf, acc[1][nt]);
            }

        // ---- BN2 + LeakyReLU ----
#pragma unroll
        for (int mi = 0; mi < 2; ++mi)
#pragma unroll
            for (int r = 0; r < 4; ++r) {
                int o = (wave * 2 + mi) * 16 + quad * 4 + r;
                float sc = jb.G2[o] * BNRS, bb = jb.B2[o];
#pragma unroll
                for (int nt = 0; nt < 4; ++nt) {
                    float y = fmaf(acc[mi][nt][r], sc, bb);
                    acc[mi][nt][r] = y > 0.f ? y : 0.1f * y;
                }
            }
    }

    // ---- epilogue ----
    unsigned short* EP = (jb.nconv == 2) ? Xt : Ct;
    if (jb.out_mode == 0) {
        unsigned short* O = (unsigned short*)jb.out;
        float os = jb.oscale;
        if (jb.nconv != 2) __syncthreads();
#pragma unroll
        for (int mi = 0; mi < 2; ++mi)
#pragma unroll
            for (int nt = 0; nt < 4; ++nt)
#pragma unroll
                for (int r = 0; r < 4; ++r) {
                    int o = (wave * 2 + mi) * 16 + quad * 4 + r;
                    int p = nt * 16 + l16;
                    EP[p * 128 + (((o >> 3) ^ (p & 15)) * 8) + (o & 7)] =
                        f2bf(acc[mi][nt][r] * os);
                }
        __syncthreads();
#pragma unroll
        for (int i = 0; i < 4; ++i) {
            int idx = t + 256 * i;
            int p = idx >> 4, ch = idx & 15;
            uint4 v = *(const uint4*)&EP[p * 128 + ((ch ^ (p & 15)) * 8)];
            *(uint4*)&O[((size_t)b * HW_DIM + p0 + p) * C_DIM + ch * 8] = v;
        }
    } else {   // out_mode 1: bf16 [b][c][pos]
        unsigned short* O = (unsigned short*)jb.out;
        if (jb.nconv != 2) __syncthreads();
#pragma unroll
        for (int mi = 0; mi < 2; ++mi)
#pragma unroll
            for (int nt = 0; nt < 4; ++nt)
#pragma unroll
                for (int r = 0; r < 4; ++r) {
                    int o = (wave * 2 + mi) * 16 + quad * 4 + r;
                    int p = nt * 16 + l16;
                    EP[o * 64 + (((p >> 3) ^ (o & 7)) * 8) + (p & 7)] =
                        f2bf(acc[mi][nt][r]);
                }
        __syncthreads();
#pragma unroll
        for (int i = 0; i < 4; ++i) {          // all 1024 chunks
            int idx = t + 256 * i;
            int o = idx >> 3, ch = idx & 7;
            uint4 v = *(const uint4*)&EP[o * 64 + ((ch ^ (o & 7)) * 8)];
            *(uint4*)&O[((size_t)b * C_DIM + o) * HW_DIM + p0 + ch * 8] = v;
        }
    }
}

// ---------------------------------------------------------------------------
// Flash attention (r18): r16 main loop UNCHANGED + tail combine.
// After writing its P/L partial, each block release-fences and bumps a
// per-(b,qblk) counter; the LAST of the NSPLIT blocks acquires and runs the
// out-conv combine for its 128 rows in-place (reusing the dead K/V LDS pool).
// Eliminates launch C (~50 µs of latency-starved partial re-reads at 0.75
// blocks/CU). Arithmetic identical to the old launch C (same sum order, same
// invl, same BN/LReLU) -> absmax must stay 0.03125.
// ---------------------------------------------------------------------------
template <int NSPLIT>
__global__ __launch_bounds__(256, 3)
void flash_attn(const unsigned short* __restrict__ Q,
                const unsigned short* __restrict__ K,
                const unsigned short* __restrict__ V,
                unsigned short* __restrict__ Pbase,
                float* __restrict__ Lbase,
                const float* __restrict__ OW,
                const float* __restrict__ OG,
                const float* __restrict__ OB,
                const float* __restrict__ RESID,
                float* __restrict__ OUT,
                unsigned int* __restrict__ Cnt)
{
    __shared__ __align__(16) unsigned short POOL[20480];  // 40 KB
    unsigned short* Kt   = POOL;                          // 16 KB
    unsigned short* Vt   = POOL + 8192;                   // 16 KB
    unsigned short* Pl   = POOL + 16384;                  // 8 KB [4][16][64]

    const int t    = threadIdx.x;
    const int wave = t >> 6;
    const int lane = t & 63;
    const int quad = lane >> 4;
    const int l16  = lane & 15;

    constexpr int KS_BITS = (NSPLIT == 8) ? 3 : 2;
    const int bid  = blockIdx.x;
    const int ks   = bid & (NSPLIT - 1);        // = XCD under round-robin
    const int b    = (bid >> KS_BITS) & 1;
    const int qblk = bid >> (KS_BITS + 1);      // 0..47
    const int q0   = qblk * 128 + wave * 32;
    const int kbeg = ks * (HW_DIM / NSPLIT);

    unsigned short* __restrict__ Po = Pbase + (size_t)ks * (2 * HW_DIM * C_DIM);
    float* __restrict__ Lo          = Lbase + (size_t)ks * (2 * HW_DIM);

    const unsigned short* Qb = Q + (size_t)b * HW_DIM * C_DIM;
    const unsigned short* Kb = K + (size_t)b * HW_DIM * C_DIM;
    const unsigned short* Vb = V + (size_t)b * C_DIM * HW_DIM;

    // Q fragments: 2 row-tiles x K=128
    short8 qf[2][4];
#pragma unroll
    for (int rt = 0; rt < 2; ++rt)
#pragma unroll
        for (int s = 0; s < 4; ++s)
            qf[rt][s] = *(const short8*)
                &Qb[(size_t)(q0 + rt * 16 + l16) * C_DIM + s * 32 + quad * 8];

    f32x4 O[2][8];
#pragma unroll
    for (int rt = 0; rt < 2; ++rt)
#pragma unroll
        for (int h = 0; h < 8; ++h) O[rt][h] = (f32x4){0.f, 0.f, 0.f, 0.f};
    float lsum[2][4] = {{0, 0, 0, 0}, {0, 0, 0, 0}};

    // Precomputed swizzled source offsets (ushort units) for staging.
    int koff[4], voff[4];
#pragma unroll
    for (int j = 0; j < 4; ++j) {
        int ci = t + 256 * j;
        int kr = ci >> 4, kc = ci & 15;
        koff[j] = kr * C_DIM + ((kc ^ (kr & 15)) << 3);
        int vr = ci >> 3, vc = ci & 7;
        voff[j] = vr * HW_DIM + ((vc ^ (vr & 7)) << 3);
    }

    const int NIT = (HW_DIM / NSPLIT) / 64;     // 12 (NSPLIT=8) / 24 (=4)
    for (int it = 0; it < NIT; ++it) {
        const int kb = kbeg + it * 64;
        const unsigned short* Ksrc = Kb + (size_t)kb * C_DIM;
        const unsigned short* Vsrc = Vb + kb;
#pragma unroll
        for (int j = 0; j < 4; ++j) {
            int ci = t + 256 * j;
            gload16(Ksrc + koff[j], &Kt[ci * 8]);
            gload16(Vsrc + voff[j], &Vt[ci * 8]);
        }
        __syncthreads();   // drains vmcnt(0): tiles landed; prev reads done

        // ---- QK^T ----
        f32x4 S[2][4];
#pragma unroll
        for (int rt = 0; rt < 2; ++rt)
#pragma unroll
            for (int n = 0; n < 4; ++n) S[rt][n] = (f32x4){0.f, 0.f, 0.f, 0.f};
#pragma unroll
        for (int n = 0; n < 4; ++n)
#pragma unroll
            for (int s = 0; s < 4; ++s) {
                short8 kf = *(const short8*)
                    &Kt[(size_t)(n * 16 + l16) * 128 + (((4 * s + quad) ^ l16) * 8)];
                S[0][n] = mfma_bf16(qf[0][s], kf, S[0][n]);
                S[1][n] = mfma_bf16(qf[1][s], kf, S[1][n]);
            }

        // ---- exp2 -> Plds (swizzled) -> pa fragments ----
        short8 pa[2][2];
#pragma unroll
        for (int rt = 0; rt < 2; ++rt) {
#pragma unroll
            for (int n = 0; n < 4; ++n)
#pragma unroll
                for (int r = 0; r < 4; ++r) {
                    float e = __builtin_amdgcn_exp2f(S[rt][n][r]);
                    lsum[rt][r] += e;
                    int row = quad * 4 + r;
                    Pl[wave * 1024 + row * 64 +
                       ((((n * 2 + (l16 >> 3)) ^ (row & 7)) << 3) | (l16 & 7))] =
                        f2bf(e);
                }
            pa[rt][0] = *(const short8*)
                &Pl[wave * 1024 + l16 * 64 + ((quad ^ (l16 & 7)) << 3)];
            pa[rt][1] = *(const short8*)
                &Pl[wave * 1024 + l16 * 64 + (((4 + quad) ^ (l16 & 7)) << 3)];
        }

        // ---- PV ----
        const int m = l16 & 7;
#pragma unroll
        for (int h = 0; h < 8; ++h) {
            short8 v0 = *(const short8*)&Vt[(size_t)(h * 16 + l16) * 64 + ((quad ^ m) * 8)];
            short8 v1 = *(const short8*)&Vt[(size_t)(h * 16 + l16) * 64 + (((quad + 4) ^ m) * 8)];
            O[0][h] = mfma_bf16(pa[0][0], v0, O[0][h]);
            O[0][h] = mfma_bf16(pa[0][1], v1, O[0][h]);
            O[1][h] = mfma_bf16(pa[1][0], v0, O[1][h]);
            O[1][h] = mfma_bf16(pa[1][1], v1, O[1][h]);
        }
        __syncthreads();
    }

    // ---- row-sum reduce across 16 cols ----
#pragma unroll
    for (int off = 1; off < 16; off <<= 1)
#pragma unroll
        for (int rt = 0; rt < 2; ++rt)
#pragma unroll
            for (int r = 0; r < 4; ++r)
                lsum[rt][r] += __shfl_xor(lsum[rt][r], off, 64);

    // ---- write P partial + L partial ----
#pragma unroll
    for (int rt = 0; rt < 2; ++rt)
#pragma unroll
        for (int r = 0; r < 4; ++r) {
            int lrow = wave * 32 + rt * 16 + quad * 4 + r;
            size_t row = (size_t)b * HW_DIM + qblk * 128 + lrow;
            if (l16 == 0) Lo[row] = lsum[rt][r];
#pragma unroll
            for (int h = 0; h < 8; ++h)
                Po[row * C_DIM + h * 16 + l16] = f2bf(O[rt][h][r]);
        }

    // ================= tail combine (last arriver per (b,qblk)) =============
    __threadfence();                     // release: my P/L visible device-wide
    __shared__ int lastflag;
    __syncthreads();                     // all waves fenced
    if (t == 0) {
        unsigned int old = atomicAdd(&Cnt[b * (HW_DIM / 128) + qblk], 1u);
        lastflag = (old == (unsigned int)(NSPLIT - 1)) ? 1 : 0;
    }
    __syncthreads();
    if (!lastflag) return;               // block-uniform
    __threadfence();                     // acquire: see the other 7 partials

    // W fragments for out-conv (direct from global fp32)
    short8 af[2][4];
#pragma unroll
    for (int mi = 0; mi < 2; ++mi) {
        int o = (wave * 2 + mi) * 16 + l16;
#pragma unroll
        for (int s = 0; s < 4; ++s)
            af[mi][s] = wfrag(OW + o * C_DIM + s * 32 + quad * 8);
    }

    unsigned short* Xc  = POOL;                  // reuse Kt (16 KB)
    float*          ivl = (float*)(POOL + 8192); // reuse Vt head (256 B)
    const float BNRS = 0.99999500003749972f;
    const size_t pstride = (size_t)2 * HW_DIM * C_DIM;

    for (int ph = 0; ph < 2; ++ph) {
        const int p0 = qblk * 128 + ph * 64;
        __syncthreads();                 // Xc/ivl reuse safe
        if (t < 64) {
            size_t li = (size_t)b * HW_DIM + p0 + t;
            float s = 0.f;
#pragma unroll
            for (int pr = 0; pr < NSPLIT; ++pr)
                s += Lbase[li + (size_t)pr * (2 * HW_DIM)];
            ivl[t] = 1.0f / s;
        }
        __syncthreads();
#pragma unroll
        for (int i = 0; i < 4; ++i) {
            int idx = t + 256 * i;
            int p = idx >> 4, ch = idx & 15;
            size_t gi = ((size_t)b * HW_DIM + p0 + p) * C_DIM + ch * 8;
            float acc8[8] = {0.f, 0.f, 0.f, 0.f, 0.f, 0.f, 0.f, 0.f};
#pragma unroll
            for (int pr = 0; pr < NSPLIT; ++pr) {
                uint4 a = *(const uint4*)&Pbase[gi + (size_t)pr * pstride];
                const unsigned int* ap = (const unsigned int*)&a;
#pragma unroll
                for (int j = 0; j < 4; ++j) {
                    acc8[2 * j]     += bf2f((unsigned short)(ap[j] & 0xFFFF));
                    acc8[2 * j + 1] += bf2f((unsigned short)(ap[j] >> 16));
                }
            }
            float s = ivl[p];
            unsigned int w[4];
#pragma unroll
            for (int j = 0; j < 4; ++j)
                w[j] = pack2(acc8[2 * j] * s, acc8[2 * j + 1] * s);
            *(uint4*)&Xc[p * 128 + ((ch ^ (p & 15)) * 8)] = *(uint4*)w;
        }
        __syncthreads();

        // out-conv GEMM: M=128 x N=64 x K=128
        f32x4 acc[2][4];
#pragma unroll
        for (int mi = 0; mi < 2; ++mi)
#pragma unroll
            for (int nt = 0; nt < 4; ++nt) acc[mi][nt] = (f32x4){0.f, 0.f, 0.f, 0.f};
#pragma unroll
        for (int nt = 0; nt < 4; ++nt)
#pragma unroll
            for (int s = 0; s < 4; ++s) {
                short8 bf = *(const short8*)
                    &Xc[(nt * 16 + l16) * 128 + (((4 * s + quad) ^ l16) * 8)];
                acc[0][nt] = mfma_bf16(af[0][s], bf, acc[0][nt]);
                acc[1][nt] = mfma_bf16(af[1][s], bf, acc[1][nt]);
            }

        // BN + LReLU + residual, fp32 [b][c][hw] store
#pragma unroll
        for (int mi = 0; mi < 2; ++mi)
#pragma unroll
            for (int r = 0; r < 4; ++r) {
                int o = (wave * 2 + mi) * 16 + quad * 4 + r;
                float sc = OG[o] * BNRS, bb = OB[o];
#pragma unroll
                for (int nt = 0; nt < 4; ++nt) {
                    float y = fmaf(acc[mi][nt][r], sc, bb);
                    y = y > 0.f ? y : 0.1f * y;
                    size_t g = ((size_t)b * C_DIM + o) * HW_DIM + p0 + nt * 16 + l16;
                    OUT[g] = y + RESID[g];
                }
            }
    }
}

// ---------------------------------------------------------------------------
extern "C" void kernel_launch(void* const* d_in, const int* in_sizes, int n_in,
                              void* d_out, int out_size, void* d_ws, size_t ws_size,
                              hipStream_t stream)
{
    const float* query = (const float*)d_in[0];
    const float* key   = (const float*)d_in[1];
    const float* q_w1 = (const float*)d_in[2];
    const float* q_g1 = (const float*)d_in[3];
    const float* q_b1 = (const float*)d_in[4];
    const float* q_w2 = (const float*)d_in[5];
    const float* q_g2 = (const float*)d_in[6];
    const float* q_b2 = (const float*)d_in[7];
    const float* k_w1 = (const float*)d_in[8];
    const float* k_g1 = (const float*)d_in[9];
    const float* k_b1 = (const float*)d_in[10];
    const float* k_w2 = (const float*)d_in[11];
    const float* k_g2 = (const float*)d_in[12];
    const float* k_b2 = (const float*)d_in[13];
    const float* v_w  = (const float*)d_in[14];
    const float* v_g  = (const float*)d_in[15];
    const float* v_b  = (const float*)d_in[16];
    const float* o_w  = (const float*)d_in[17];
    const float* o_g  = (const float*)d_in[18];
    const float* o_b  = (const float*)d_in[19];

    // Workspace layout (contiguous):
    //   [ P partials: nsplit x 3145728 B ][ Qbf ][ Kbf ][ Vbf ]
    //   [ L: nsplit x 49152 B ][ Cnt: 384 B ]
    const size_t PPART = (size_t)2 * HW_DIM * C_DIM * 2;  // 3,145,728 B
    const size_t LPART = (size_t)2 * HW_DIM * 4;          // 49,152 B
    const int nsplit = (ws_size >= 11 * PPART + 8 * LPART + 512) ? 8 : 4;

    char* ws = (char*)d_ws;
    unsigned short* Pbase = (unsigned short*)ws;
    unsigned short* Qbf = (unsigned short*)(ws + (size_t)nsplit * PPART);
    unsigned short* Kbf = (unsigned short*)(ws + (size_t)nsplit * PPART + PPART);
    unsigned short* Vbf = (unsigned short*)(ws + (size_t)nsplit * PPART + 2 * PPART);
    float*          Lbase = (float*)(ws + (size_t)nsplit * PPART + 3 * PPART);
    unsigned int*   Cnt = (unsigned int*)(ws + (size_t)nsplit * PPART + 3 * PPART
                                             + (size_t)nsplit * LPART);
    float* outp = (float*)d_out;

    const float qscale = 0.08838834764831845f * 1.44269504088896340f;

    // Counters must be zero before flash (graph-capturable async memset).
    hipMemsetAsync(Cnt, 0, 2 * (HW_DIM / 128) * sizeof(unsigned int), stream);

    // Launch A: fused double-convs. z0: query->conv1->conv2->Qbf (scaled);
    // z1: key->conv1->conv2->Kbf; z2: key->v-conv->Vbf.
    {
        MJobs J{};
        J.j[0] = {query, nullptr, q_w1, q_g1, q_b1, q_w2, q_g2, q_b2,
                  (void*)Qbf, nullptr, qscale, 0, 0, 0, 2};
        J.j[1] = {key,   nullptr, k_w1, k_g1, k_b1, k_w2, k_g2, k_b2,
                  (void*)Kbf, nullptr, 1.0f,   0, 0, 0, 2};
        J.j[2] = {key,   nullptr, v_w,  v_g,  v_b,  nullptr, nullptr, nullptr,
                  (void*)Vbf, nullptr, 1.0f,   0, 1, 0, 1};
        hipLaunchKernelGGL(conv_mfma, dim3(HW_DIM / 64, 2, 3), dim3(256),
                           0, stream, J);
    }

    // Flash + tail combine: 4-wave blocks, 128 q-rows, NSPLIT-way k-split.
    if (nsplit == 8) {
        hipLaunchKernelGGL(HIP_KERNEL_NAME(flash_attn<8>),
                           dim3(2 * (HW_DIM / 128) * 8), dim3(256),
                           0, stream, Qbf, Kbf, Vbf, Pbase, Lbase,
                           o_w, o_g, o_b, query, outp, Cnt);
    } else {
        hipLaunchKernelGGL(HIP_KERNEL_NAME(flash_attn<4>),
                           dim3(2 * (HW_DIM / 128) * 4), dim3(256),
                           0, stream, Qbf, Kbf, Vbf, Pbase, Lbase,
                           o_w, o_g, o_b, query, outp, Cnt);
    }
}

// Round 5
// 186.474 us; speedup vs baseline: 1.7685x; 1.7685x over previous
//
#include <hip/hip_runtime.h>

#define C_DIM 128
#define HW_DIM 6144

typedef __attribute__((ext_vector_type(8))) short short8;
typedef __attribute__((ext_vector_type(4))) float f32x4;

static __device__ __forceinline__ unsigned short f2bf(float x) {
    unsigned int u = __builtin_bit_cast(unsigned int, x);
    u = (u + 0x7FFFu + ((u >> 16) & 1u)) >> 16;
    return (unsigned short)u;
}
static __device__ __forceinline__ float bf2f(unsigned short u) {
    unsigned int x = ((unsigned int)u) << 16;
    return __builtin_bit_cast(float, x);
}
static __device__ __forceinline__ unsigned int pack2(float a, float b) {
    return (unsigned int)f2bf(a) | ((unsigned int)f2bf(b) << 16);
}
static __device__ __forceinline__ f32x4 mfma_bf16(short8 a, short8 b, f32x4 c) {
    return __builtin_amdgcn_mfma_f32_16x16x32_bf16(a, b, c, 0, 0, 0);
}
// async global->LDS, 16B per lane; LDS dest is wave-uniform-base + lane*16,
// global source is per-lane (pre-swizzled).
static __device__ __forceinline__ void gload16(const unsigned short* g,
                                               unsigned short* l) {
    __builtin_amdgcn_global_load_lds(
        (const __attribute__((address_space(1))) unsigned int*)g,
        (__attribute__((address_space(3))) unsigned int*)l, 16, 0, 0);
}
// Load one MFMA A-fragment (bf16) directly from global fp32 W[o][c]:
// lane (l16,quad) of row-tile base `o` needs W[o][c0 .. c0+7], c0=s*32+quad*8.
static __device__ __forceinline__ short8 wfrag(const float* Wrow) {
    float4 a = *(const float4*)Wrow;
    float4 b = *(const float4*)(Wrow + 4);
    unsigned int u[4] = {pack2(a.x, a.y), pack2(a.z, a.w),
                         pack2(b.x, b.y), pack2(b.z, b.w)};
    return *(const short8*)u;
}

// ---------------------------------------------------------------------------
// Fused (1x1 conv -> BN -> LReLU) x nconv kernel.
// r19: templated on NPARTS. NPARTS=0 -> conv path (in_mode 0/1), combine
// branch compiled out. NPARTS=4/8 -> combine path (in_mode 2) with FULLY
// UNROLLED partial loads: 32 independent uint4 loads in flight per thread
// instead of 8 serialized dependent latency chains (r18 post-mortem: the
// runtime-nparts loop was why launch C burned ~50 µs on ~6 µs of traffic).
// in_mode : 0 = X fp32 [b][c][hw] (transpose-stage)
//           1 = X bf16 [b][pos][c] (direct stage)
//           2 = combine: sum of NPARTS partials [pos][c] bf16 * invL[pos]
// out_mode: 0 = bf16 [b][pos][c] * oscale
//           1 = bf16 [b][c][pos]
//           2 = fp32 [b][c][hw] + residual
// ---------------------------------------------------------------------------
struct MJob {
    const void* X;          // input (or P-partials base for in_mode 2)
    const float* L;         // L-partials base (in_mode 2)
    const float* W1; const float* G1; const float* B1;
    const float* W2; const float* G2; const float* B2;
    void* out; const float* resid;
    float oscale; int in_mode; int out_mode; int nconv;
};
struct MJobs { MJob j[3]; };

template <int NPARTS>
__global__ __launch_bounds__(256)
void conv_mfma(MJobs jobs)
{
    const MJob jb = (blockIdx.z == 0) ? jobs.j[0]
                  : (blockIdx.z == 1) ? jobs.j[1] : jobs.j[2];

    __shared__ __align__(16) unsigned short Xt[64 * 128];   // 16 KB conv1 B
    __shared__ __align__(16) unsigned short Ct[64 * 128];   // 16 KB mid / epi
    __shared__ float invl[64];

    const int t    = threadIdx.x;
    const int b    = blockIdx.y;
    const int p0   = blockIdx.x * 64;
    const int wave = t >> 6;
    const int lane = t & 63;
    const int quad = lane >> 4;
    const int l16  = lane & 15;

    // ---- W fragments direct from global (rows o = (wave*2+mi)*16+l16) ----
    short8 af1[2][4], af2[2][4];
#pragma unroll
    for (int mi = 0; mi < 2; ++mi) {
        int o = (wave * 2 + mi) * 16 + l16;
#pragma unroll
        for (int s = 0; s < 4; ++s)
            af1[mi][s] = wfrag(jb.W1 + o * C_DIM + s * 32 + quad * 8);
    }
    if (jb.nconv == 2) {
#pragma unroll
        for (int mi = 0; mi < 2; ++mi) {
            int o = (wave * 2 + mi) * 16 + l16;
#pragma unroll
            for (int s = 0; s < 4; ++s)
                af2[mi][s] = wfrag(jb.W2 + o * C_DIM + s * 32 + quad * 8);
        }
    }

    // ---- stage X per in_mode -> bf16 Xt[p][chunk^(p&15)] ----
    if constexpr (NPARTS == 0) {
        if (jb.in_mode == 0) {
            const float* Xg = (const float*)jb.X + (size_t)b * C_DIM * HW_DIM;
#pragma unroll
            for (int i = 0; i < 8; ++i) {
                int f = i * 1024 + t * 4;     // c = f>>6, p = f&63 (mult of 4)
                int c = f >> 6, p = f & 63;
                float4 x4 = *(const float4*)&Xg[(size_t)c * HW_DIM + p0 + p];
                float xv[4] = {x4.x, x4.y, x4.z, x4.w};
#pragma unroll
                for (int j = 0; j < 4; ++j) {
                    int pp = p + j;
                    Xt[pp * 128 + (((c >> 3) ^ (pp & 15)) * 8) + (c & 7)] = f2bf(xv[j]);
                }
            }
        } else {
            const unsigned short* Xg = (const unsigned short*)jb.X;
#pragma unroll
            for (int i = 0; i < 4; ++i) {
                int idx = t + 256 * i;        // p = idx>>4, ch = idx&15
                int p = idx >> 4, ch = idx & 15;
                uint4 v = *(const uint4*)&Xg[((size_t)b * HW_DIM + p0 + p) * C_DIM + ch * 8];
                *(uint4*)&Xt[p * 128 + ((ch ^ (p & 15)) * 8)] = v;
            }
        }
    } else {
        // ---- combine path: all loads unrolled & independent ----
        if (t < 64) {
            size_t li = (size_t)b * HW_DIM + p0 + t;
            float s = 0.f;
#pragma unroll
            for (int pr = 0; pr < NPARTS; ++pr)
                s += jb.L[li + (size_t)pr * (2 * HW_DIM)];
            invl[t] = 1.0f / s;
        }
        __syncthreads();
        const unsigned short* A0 = (const unsigned short*)jb.X;
        const size_t pstride = (size_t)2 * HW_DIM * C_DIM;   // ushorts per part
#pragma unroll
        for (int i = 0; i < 4; ++i) {
            int idx = t + 256 * i;
            int p = idx >> 4, ch = idx & 15;
            size_t gi = ((size_t)b * HW_DIM + p0 + p) * C_DIM + ch * 8;
            float acc8[8] = {0.f, 0.f, 0.f, 0.f, 0.f, 0.f, 0.f, 0.f};
#pragma unroll
            for (int pr = 0; pr < NPARTS; ++pr) {
                uint4 a = *(const uint4*)&A0[gi + (size_t)pr * pstride];
                const unsigned int* ap = (const unsigned int*)&a;
#pragma unroll
                for (int j = 0; j < 4; ++j) {
                    acc8[2 * j]     += bf2f((unsigned short)(ap[j] & 0xFFFF));
                    acc8[2 * j + 1] += bf2f((unsigned short)(ap[j] >> 16));
                }
            }
            float s = invl[p];
            unsigned int w[4];
#pragma unroll
            for (int j = 0; j < 4; ++j)
                w[j] = pack2(acc8[2 * j] * s, acc8[2 * j + 1] * s);
            *(uint4*)&Xt[p * 128 + ((ch ^ (p & 15)) * 8)] = *(uint4*)w;
        }
    }
    __syncthreads();

    const float BNRS = 0.99999500003749972f;  // 1/sqrt(1 + 1e-5)

    // ---- conv1 GEMM: wave does m-tiles {2w,2w+1} x 4 n-tiles, K=128 ----
    f32x4 acc[2][4];
#pragma unroll
    for (int mi = 0; mi < 2; ++mi)
#pragma unroll
        for (int nt = 0; nt < 4; ++nt) acc[mi][nt] = (f32x4){0.f, 0.f, 0.f, 0.f};
#pragma unroll
    for (int nt = 0; nt < 4; ++nt)
#pragma unroll
        for (int s = 0; s < 4; ++s) {
            short8 bf = *(const short8*)
                &Xt[(nt * 16 + l16) * 128 + (((4 * s + quad) ^ l16) * 8)];
            acc[0][nt] = mfma_bf16(af1[0][s], bf, acc[0][nt]);
            acc[1][nt] = mfma_bf16(af1[1][s], bf, acc[1][nt]);
        }

    // ---- BN1 + LeakyReLU ----
#pragma unroll
    for (int mi = 0; mi < 2; ++mi)
#pragma unroll
        for (int r = 0; r < 4; ++r) {
            int o = (wave * 2 + mi) * 16 + quad * 4 + r;
            float sc = jb.G1[o] * BNRS, bb = jb.B1[o];
#pragma unroll
            for (int nt = 0; nt < 4; ++nt) {
                float y = fmaf(acc[mi][nt][r], sc, bb);
                acc[mi][nt][r] = y > 0.f ? y : 0.1f * y;
            }
        }

    if (jb.nconv == 2) {
        // ---- mid -> Ct in B-operand swizzle ----
#pragma unroll
        for (int mi = 0; mi < 2; ++mi)
#pragma unroll
            for (int nt = 0; nt < 4; ++nt)
#pragma unroll
                for (int r = 0; r < 4; ++r) {
                    int o = (wave * 2 + mi) * 16 + quad * 4 + r;
                    int p = nt * 16 + l16;
                    Ct[p * 128 + (((o >> 3) ^ (p & 15)) * 8) + (o & 7)] =
                        f2bf(acc[mi][nt][r]);
                }
        __syncthreads();

        // ---- conv2 GEMM from Ct ----
#pragma unroll
        for (int mi = 0; mi < 2; ++mi)
#pragma unroll
            for (int nt = 0; nt < 4; ++nt) acc[mi][nt] = (f32x4){0.f, 0.f, 0.f, 0.f};
#pragma unroll
        for (int nt = 0; nt < 4; ++nt)
#pragma unroll
            for (int s = 0; s < 4; ++s) {
                short8 bf = *(const short8*)
                    &Ct[(nt * 16 + l16) * 128 + (((4 * s + quad) ^ l16) * 8)];
                acc[0][nt] = mfma_bf16(af2[0][s], bf, acc[0][nt]);
                acc[1][nt] = mfma_bf16(af2[1][s], bf, acc[1][nt]);
            }

        // ---- BN2 + LeakyReLU ----
#pragma unroll
        for (int mi = 0; mi < 2; ++mi)
#pragma unroll
            for (int r = 0; r < 4; ++r) {
                int o = (wave * 2 + mi) * 16 + quad * 4 + r;
                float sc = jb.G2[o] * BNRS, bb = jb.B2[o];
#pragma unroll
                for (int nt = 0; nt < 4; ++nt) {
                    float y = fmaf(acc[mi][nt][r], sc, bb);
                    acc[mi][nt][r] = y > 0.f ? y : 0.1f * y;
                }
            }
    }

    // ---- epilogue ----
    unsigned short* EP = (jb.nconv == 2) ? Xt : Ct;
    if (jb.out_mode == 0) {
        unsigned short* O = (unsigned short*)jb.out;
        float os = jb.oscale;
        if (jb.nconv != 2) __syncthreads();
#pragma unroll
        for (int mi = 0; mi < 2; ++mi)
#pragma unroll
            for (int nt = 0; nt < 4; ++nt)
#pragma unroll
                for (int r = 0; r < 4; ++r) {
                    int o = (wave * 2 + mi) * 16 + quad * 4 + r;
                    int p = nt * 16 + l16;
                    EP[p * 128 + (((o >> 3) ^ (p & 15)) * 8) + (o & 7)] =
                        f2bf(acc[mi][nt][r] * os);
                }
        __syncthreads();
#pragma unroll
        for (int i = 0; i < 4; ++i) {
            int idx = t + 256 * i;
            int p = idx >> 4, ch = idx & 15;
            uint4 v = *(const uint4*)&EP[p * 128 + ((ch ^ (p & 15)) * 8)];
            *(uint4*)&O[((size_t)b * HW_DIM + p0 + p) * C_DIM + ch * 8] = v;
        }
    } else if (jb.out_mode == 1) {
        unsigned short* O = (unsigned short*)jb.out;
        if (jb.nconv != 2) __syncthreads();
#pragma unroll
        for (int mi = 0; mi < 2; ++mi)
#pragma unroll
            for (int nt = 0; nt < 4; ++nt)
#pragma unroll
                for (int r = 0; r < 4; ++r) {
                    int o = (wave * 2 + mi) * 16 + quad * 4 + r;
                    int p = nt * 16 + l16;
                    EP[o * 64 + (((p >> 3) ^ (o & 7)) * 8) + (p & 7)] =
                        f2bf(acc[mi][nt][r]);
                }
        __syncthreads();
#pragma unroll
        for (int i = 0; i < 4; ++i) {          // all 1024 chunks
            int idx = t + 256 * i;
            int o = idx >> 3, ch = idx & 7;
            uint4 v = *(const uint4*)&EP[o * 64 + ((ch ^ (o & 7)) * 8)];
            *(uint4*)&O[((size_t)b * C_DIM + o) * HW_DIM + p0 + ch * 8] = v;
        }
    } else {
        float* O = (float*)jb.out;
#pragma unroll
        for (int mi = 0; mi < 2; ++mi)
#pragma unroll
            for (int nt = 0; nt < 4; ++nt)
#pragma unroll
                for (int r = 0; r < 4; ++r) {
                    int o = (wave * 2 + mi) * 16 + quad * 4 + r;
                    size_t g = ((size_t)b * C_DIM + o) * HW_DIM + p0 + nt * 16 + l16;
                    O[g] = acc[mi][nt][r] + jb.resid[g];
                }
    }
}

// ---------------------------------------------------------------------------
// Flash attention (r16 EXACT — proven 59 µs twice; r18's in-kernel tail
// combine with device fences was a 4x regression: threadfence's L2
// writeback/invalidate thrashes co-resident blocks' K/V L2 working set).
// ---------------------------------------------------------------------------
template <int NSPLIT>
__global__ __launch_bounds__(256, 3)
void flash_attn(const unsigned short* __restrict__ Q,
                const unsigned short* __restrict__ K,
                const unsigned short* __restrict__ V,
                unsigned short* __restrict__ Pbase,
                float* __restrict__ Lbase)
{
    __shared__ __align__(16) unsigned short Kt[64 * 128];     // 16 KB
    __shared__ __align__(16) unsigned short Vt[128 * 64];     // 16 KB
    __shared__ __align__(16) unsigned short Plds[4][16][64];  // 8 KB swizzled

    const int t    = threadIdx.x;
    const int wave = t >> 6;
    const int lane = t & 63;
    const int quad = lane >> 4;
    const int l16  = lane & 15;

    constexpr int KS_BITS = (NSPLIT == 8) ? 3 : 2;
    const int bid  = blockIdx.x;
    const int ks   = bid & (NSPLIT - 1);        // = XCD under round-robin
    const int b    = (bid >> KS_BITS) & 1;
    const int qblk = bid >> (KS_BITS + 1);      // 0..47
    const int q0   = qblk * 128 + wave * 32;
    const int kbeg = ks * (HW_DIM / NSPLIT);

    unsigned short* __restrict__ Po = Pbase + (size_t)ks * (2 * HW_DIM * C_DIM);
    float* __restrict__ Lo          = Lbase + (size_t)ks * (2 * HW_DIM);

    const unsigned short* Qb = Q + (size_t)b * HW_DIM * C_DIM;
    const unsigned short* Kb = K + (size_t)b * HW_DIM * C_DIM;
    const unsigned short* Vb = V + (size_t)b * C_DIM * HW_DIM;

    // Q fragments: 2 row-tiles x K=128
    short8 qf[2][4];
#pragma unroll
    for (int rt = 0; rt < 2; ++rt)
#pragma unroll
        for (int s = 0; s < 4; ++s)
            qf[rt][s] = *(const short8*)
                &Qb[(size_t)(q0 + rt * 16 + l16) * C_DIM + s * 32 + quad * 8];

    f32x4 O[2][8];
#pragma unroll
    for (int rt = 0; rt < 2; ++rt)
#pragma unroll
        for (int h = 0; h < 8; ++h) O[rt][h] = (f32x4){0.f, 0.f, 0.f, 0.f};
    float lsum[2][4] = {{0, 0, 0, 0}, {0, 0, 0, 0}};

    // Precomputed swizzled source offsets (ushort units) for staging.
    int koff[4], voff[4];
#pragma unroll
    for (int j = 0; j < 4; ++j) {
        int ci = t + 256 * j;
        int kr = ci >> 4, kc = ci & 15;
        koff[j] = kr * C_DIM + ((kc ^ (kr & 15)) << 3);
        int vr = ci >> 3, vc = ci & 7;
        voff[j] = vr * HW_DIM + ((vc ^ (vr & 7)) << 3);
    }

    const int NIT = (HW_DIM / NSPLIT) / 64;     // 12 (NSPLIT=8) / 24 (=4)
    for (int it = 0; it < NIT; ++it) {
        const int kb = kbeg + it * 64;
        const unsigned short* Ksrc = Kb + (size_t)kb * C_DIM;
        const unsigned short* Vsrc = Vb + kb;
#pragma unroll
        for (int j = 0; j < 4; ++j) {
            int ci = t + 256 * j;
            gload16(Ksrc + koff[j], &Kt[ci * 8]);
            gload16(Vsrc + voff[j], &Vt[ci * 8]);
        }
        __syncthreads();   // drains vmcnt(0): tiles landed; prev reads done

        // ---- QK^T: S[rt][n] over 64 k-cols, K=128 ----
        f32x4 S[2][4];
#pragma unroll
        for (int rt = 0; rt < 2; ++rt)
#pragma unroll
            for (int n = 0; n < 4; ++n) S[rt][n] = (f32x4){0.f, 0.f, 0.f, 0.f};
#pragma unroll
        for (int n = 0; n < 4; ++n)
#pragma unroll
            for (int s = 0; s < 4; ++s) {
                short8 kf = *(const short8*)
                    &Kt[(size_t)(n * 16 + l16) * 128 + (((4 * s + quad) ^ l16) * 8)];
                S[0][n] = mfma_bf16(qf[0][s], kf, S[0][n]);
                S[1][n] = mfma_bf16(qf[1][s], kf, S[1][n]);
            }

        // ---- exp2 -> Plds (swizzled) -> pa fragments ----
        short8 pa[2][2];
#pragma unroll
        for (int rt = 0; rt < 2; ++rt) {
#pragma unroll
            for (int n = 0; n < 4; ++n)
#pragma unroll
                for (int r = 0; r < 4; ++r) {
                    float e = __builtin_amdgcn_exp2f(S[rt][n][r]);
                    lsum[rt][r] += e;
                    int row = quad * 4 + r;
                    Plds[wave][row][(((n * 2 + (l16 >> 3)) ^ (row & 7)) << 3) | (l16 & 7)] =
                        f2bf(e);
                }
            pa[rt][0] = *(const short8*)&Plds[wave][l16][((quad       ^ (l16 & 7)) << 3)];
            pa[rt][1] = *(const short8*)&Plds[wave][l16][(((4 + quad) ^ (l16 & 7)) << 3)];
        }

        // ---- PV ----
        const int m = l16 & 7;
#pragma unroll
        for (int h = 0; h < 8; ++h) {
            short8 v0 = *(const short8*)&Vt[(size_t)(h * 16 + l16) * 64 + ((quad ^ m) * 8)];
            short8 v1 = *(const short8*)&Vt[(size_t)(h * 16 + l16) * 64 + (((quad + 4) ^ m) * 8)];
            O[0][h] = mfma_bf16(pa[0][0], v0, O[0][h]);
            O[0][h] = mfma_bf16(pa[0][1], v1, O[0][h]);
            O[1][h] = mfma_bf16(pa[1][0], v0, O[1][h]);
            O[1][h] = mfma_bf16(pa[1][1], v1, O[1][h]);
        }
        __syncthreads();   // all waves done reading before next overwrite
    }

    // ---- row-sum reduce across 16 cols ----
#pragma unroll
    for (int off = 1; off < 16; off <<= 1)
#pragma unroll
        for (int rt = 0; rt < 2; ++rt)
#pragma unroll
            for (int r = 0; r < 4; ++r)
                lsum[rt][r] += __shfl_xor(lsum[rt][r], off, 64);

    // ---- write P partial + L partial ----
#pragma unroll
    for (int rt = 0; rt < 2; ++rt)
#pragma unroll
        for (int r = 0; r < 4; ++r) {
            int lrow = wave * 32 + rt * 16 + quad * 4 + r;
            size_t row = (size_t)b * HW_DIM + qblk * 128 + lrow;
            if (l16 == 0) Lo[row] = lsum[rt][r];
#pragma unroll
            for (int h = 0; h < 8; ++h)
                Po[row * C_DIM + h * 16 + l16] = f2bf(O[rt][h][r]);
        }
}

// ---------------------------------------------------------------------------
extern "C" void kernel_launch(void* const* d_in, const int* in_sizes, int n_in,
                              void* d_out, int out_size, void* d_ws, size_t ws_size,
                              hipStream_t stream)
{
    const float* query = (const float*)d_in[0];
    const float* key   = (const float*)d_in[1];
    const float* q_w1 = (const float*)d_in[2];
    const float* q_g1 = (const float*)d_in[3];
    const float* q_b1 = (const float*)d_in[4];
    const float* q_w2 = (const float*)d_in[5];
    const float* q_g2 = (const float*)d_in[6];
    const float* q_b2 = (const float*)d_in[7];
    const float* k_w1 = (const float*)d_in[8];
    const float* k_g1 = (const float*)d_in[9];
    const float* k_b1 = (const float*)d_in[10];
    const float* k_w2 = (const float*)d_in[11];
    const float* k_g2 = (const float*)d_in[12];
    const float* k_b2 = (const float*)d_in[13];
    const float* v_w  = (const float*)d_in[14];
    const float* v_g  = (const float*)d_in[15];
    const float* v_b  = (const float*)d_in[16];
    const float* o_w  = (const float*)d_in[17];
    const float* o_g  = (const float*)d_in[18];
    const float* o_b  = (const float*)d_in[19];

    // Workspace layout (contiguous):
    //   [ P partials: nsplit x 3145728 B ][ Qbf ][ Kbf ][ Vbf ][ L: nsplit x 49152 B ]
    const size_t PPART = (size_t)2 * HW_DIM * C_DIM * 2;  // 3,145,728 B
    const size_t LPART = (size_t)2 * HW_DIM * 4;          // 49,152 B
    const int nsplit = (ws_size >= 11 * PPART + 8 * LPART) ? 8 : 4;

    char* ws = (char*)d_ws;
    unsigned short* Pbase = (unsigned short*)ws;
    unsigned short* Qbf = (unsigned short*)(ws + (size_t)nsplit * PPART);
    unsigned short* Kbf = (unsigned short*)(ws + (size_t)nsplit * PPART + PPART);
    unsigned short* Vbf = (unsigned short*)(ws + (size_t)nsplit * PPART + 2 * PPART);
    float*          Lbase = (float*)(ws + (size_t)nsplit * PPART + 3 * PPART);
    float* outp = (float*)d_out;

    const float qscale = 0.08838834764831845f * 1.44269504088896340f;

    // Launch A: fused double-convs. z0: query->conv1->conv2->Qbf (scaled);
    // z1: key->conv1->conv2->Kbf; z2: key->v-conv->Vbf.
    {
        MJobs J{};
        J.j[0] = {query, nullptr, q_w1, q_g1, q_b1, q_w2, q_g2, q_b2,
                  (void*)Qbf, nullptr, qscale, 0, 0, 2};
        J.j[1] = {key,   nullptr, k_w1, k_g1, k_b1, k_w2, k_g2, k_b2,
                  (void*)Kbf, nullptr, 1.0f,   0, 0, 2};
        J.j[2] = {key,   nullptr, v_w,  v_g,  v_b,  nullptr, nullptr, nullptr,
                  (void*)Vbf, nullptr, 1.0f,   0, 1, 1};
        hipLaunchKernelGGL(HIP_KERNEL_NAME(conv_mfma<0>),
                           dim3(HW_DIM / 64, 2, 3), dim3(256), 0, stream, J);
    }

    // Flash: 4-wave blocks, 128 q-rows each, NSPLIT-way k-split.
    if (nsplit == 8) {
        hipLaunchKernelGGL(HIP_KERNEL_NAME(flash_attn<8>),
                           dim3(2 * (HW_DIM / 128) * 8), dim3(256),
                           0, stream, Qbf, Kbf, Vbf, Pbase, Lbase);
    } else {
        hipLaunchKernelGGL(HIP_KERNEL_NAME(flash_attn<4>),
                           dim3(2 * (HW_DIM / 128) * 4), dim3(256),
                           0, stream, Qbf, Kbf, Vbf, Pbase, Lbase);
    }

    // Launch C: combine nsplit partials -> out-conv + residual.
    // NPARTS templated -> partial loads fully unrolled (32 uint4 in flight).
    {
        MJobs J{};
        J.j[0] = {Pbase, Lbase, o_w, o_g, o_b, nullptr, nullptr, nullptr,
                  (void*)outp, query, 1.0f, 2, 2, 1};
        J.j[1] = J.j[0];
        J.j[2] = J.j[0];
        if (nsplit == 8) {
            hipLaunchKernelGGL(HIP_KERNEL_NAME(conv_mfma<8>),
                               dim3(HW_DIM / 64, 2, 1), dim3(256), 0, stream, J);
        } else {
            hipLaunchKernelGGL(HIP_KERNEL_NAME(conv_mfma<4>),
                               dim3(HW_DIM / 64, 2, 1), dim3(256), 0, stream, J);
        }
    }
}

// Round 8
// 174.123 us; speedup vs baseline: 1.8939x; 1.0709x over previous
//
#include <hip/hip_runtime.h>

#define C_DIM 128
#define HW_DIM 6144

typedef __attribute__((ext_vector_type(8))) short short8;
typedef __attribute__((ext_vector_type(4))) float f32x4;

static __device__ __forceinline__ unsigned short f2bf(float x) {
    unsigned int u = __builtin_bit_cast(unsigned int, x);
    u = (u + 0x7FFFu + ((u >> 16) & 1u)) >> 16;
    return (unsigned short)u;
}
static __device__ __forceinline__ float bf2f(unsigned short u) {
    unsigned int x = ((unsigned int)u) << 16;
    return __builtin_bit_cast(float, x);
}
static __device__ __forceinline__ unsigned int pack2(float a, float b) {
    return (unsigned int)f2bf(a) | ((unsigned int)f2bf(b) << 16);
}
static __device__ __forceinline__ f32x4 mfma_bf16(short8 a, short8 b, f32x4 c) {
    return __builtin_amdgcn_mfma_f32_16x16x32_bf16(a, b, c, 0, 0, 0);
}
// async global->LDS, 16B per lane; LDS dest linear, global source pre-swizzled.
static __device__ __forceinline__ void gload16(const unsigned short* g,
                                               unsigned short* l) {
    __builtin_amdgcn_global_load_lds(
        (const __attribute__((address_space(1))) unsigned int*)g,
        (__attribute__((address_space(3))) unsigned int*)l, 16, 0, 0);
}
// MFMA A-fragment (bf16) directly from global fp32 W[o][c].
static __device__ __forceinline__ short8 wfrag(const float* Wrow) {
    float4 a = *(const float4*)Wrow;
    float4 b = *(const float4*)(Wrow + 4);
    unsigned int u[4] = {pack2(a.x, a.y), pack2(a.z, a.w),
                         pack2(b.x, b.y), pack2(b.z, b.w)};
    return *(const short8*)u;
}

// ---------------------------------------------------------------------------
// Fused (1x1 conv -> BN -> LReLU) x nconv kernel.
// r22: templated on <NPARTS, NTILES>. NTILES = output positions / 16.
//   A (QKV projections): <0,4>  — N=64/block, 576 blocks (r17-proven).
//   C (combine):         <8,2>  — N=32/block, 384 blocks. r19 showed the
//     8-partial combine is outstanding-load limited at 0.75 blocks/CU;
//     halving the tile doubles block count -> 2x memory parallelism.
// ---------------------------------------------------------------------------
struct MJob {
    const void* X;          // input (or P-partials base for in_mode 2)
    const float* L;         // L-partials base (in_mode 2)
    const float* W1; const float* G1; const float* B1;
    const float* W2; const float* G2; const float* B2;
    void* out; const float* resid;
    float oscale; int in_mode; int out_mode; int nconv;
};
struct MJobs { MJob j[3]; };

template <int NPARTS, int NTILES>
__global__ __launch_bounds__(256)
void conv_mfma(MJobs jobs)
{
    constexpr int NPOS = NTILES * 16;

    const MJob jb = (blockIdx.z == 0) ? jobs.j[0]
                  : (blockIdx.z == 1) ? jobs.j[1] : jobs.j[2];

    __shared__ __align__(16) unsigned short Xt[64 * 128];   // 16 KB B tile
    __shared__ __align__(16) unsigned short Ct[64 * 128];   // 16 KB mid/epi
    __shared__ float invl[64];

    const int t    = threadIdx.x;
    const int b    = blockIdx.y;
    const int p0   = blockIdx.x * NPOS;
    const int wave = t >> 6;
    const int lane = t & 63;
    const int quad = lane >> 4;
    const int l16  = lane & 15;

    // ---- W fragments direct from global (rows o = (wave*2+mi)*16+l16) ----
    short8 af1[2][4], af2[2][4];
#pragma unroll
    for (int mi = 0; mi < 2; ++mi) {
        int o = (wave * 2 + mi) * 16 + l16;
#pragma unroll
        for (int s = 0; s < 4; ++s)
            af1[mi][s] = wfrag(jb.W1 + o * C_DIM + s * 32 + quad * 8);
    }
    if (jb.nconv == 2) {
#pragma unroll
        for (int mi = 0; mi < 2; ++mi) {
            int o = (wave * 2 + mi) * 16 + l16;
#pragma unroll
            for (int s = 0; s < 4; ++s)
                af2[mi][s] = wfrag(jb.W2 + o * C_DIM + s * 32 + quad * 8);
        }
    }

    // ---- stage X -> bf16 Xt[p][chunk^(p&15)] ----
    if constexpr (NPARTS == 0) {
        if (jb.in_mode == 0) {
            const float* Xg = (const float*)jb.X + (size_t)b * C_DIM * HW_DIM;
#pragma unroll
            for (int i = 0; i < 8; ++i) {
                int f = i * 1024 + t * 4;     // c = f>>6, p = f&63 (NPOS=64)
                int c = f >> 6, p = f & 63;
                float4 x4 = *(const float4*)&Xg[(size_t)c * HW_DIM + p0 + p];
                float xv[4] = {x4.x, x4.y, x4.z, x4.w};
#pragma unroll
                for (int j = 0; j < 4; ++j) {
                    int pp = p + j;
                    Xt[pp * 128 + (((c >> 3) ^ (pp & 15)) * 8) + (c & 7)] = f2bf(xv[j]);
                }
            }
        } else {
            const unsigned short* Xg = (const unsigned short*)jb.X;
#pragma unroll
            for (int i = 0; i < NTILES; ++i) {
                int idx = t + 256 * i;        // p = idx>>4, ch = idx&15
                int p = idx >> 4, ch = idx & 15;
                uint4 v = *(const uint4*)&Xg[((size_t)b * HW_DIM + p0 + p) * C_DIM + ch * 8];
                *(uint4*)&Xt[p * 128 + ((ch ^ (p & 15)) * 8)] = v;
            }
        }
    } else {
        // ---- combine path: fully unrolled partial loads (r19) ----
        if (t < NPOS) {
            size_t li = (size_t)b * HW_DIM + p0 + t;
            float s = 0.f;
#pragma unroll
            for (int pr = 0; pr < NPARTS; ++pr)
                s += jb.L[li + (size_t)pr * (2 * HW_DIM)];
            invl[t] = 1.0f / s;
        }
        __syncthreads();
        const unsigned short* A0 = (const unsigned short*)jb.X;
        const size_t pstride = (size_t)2 * HW_DIM * C_DIM;   // ushorts per part
#pragma unroll
        for (int i = 0; i < NTILES; ++i) {
            int idx = t + 256 * i;
            int p = idx >> 4, ch = idx & 15;
            size_t gi = ((size_t)b * HW_DIM + p0 + p) * C_DIM + ch * 8;
            float acc8[8] = {0.f, 0.f, 0.f, 0.f, 0.f, 0.f, 0.f, 0.f};
#pragma unroll
            for (int pr = 0; pr < NPARTS; ++pr) {
                uint4 a = *(const uint4*)&A0[gi + (size_t)pr * pstride];
                const unsigned int* ap = (const unsigned int*)&a;
#pragma unroll
                for (int j = 0; j < 4; ++j) {
                    acc8[2 * j]     += bf2f((unsigned short)(ap[j] & 0xFFFF));
                    acc8[2 * j + 1] += bf2f((unsigned short)(ap[j] >> 16));
                }
            }
            float s = invl[p];
            unsigned int w[4];
#pragma unroll
            for (int j = 0; j < 4; ++j)
                w[j] = pack2(acc8[2 * j] * s, acc8[2 * j + 1] * s);
            *(uint4*)&Xt[p * 128 + ((ch ^ (p & 15)) * 8)] = *(uint4*)w;
        }
    }
    __syncthreads();

    const float BNRS = 0.99999500003749972f;  // 1/sqrt(1 + 1e-5)

    // ---- conv1 GEMM ----
    f32x4 acc[2][NTILES];
#pragma unroll
    for (int mi = 0; mi < 2; ++mi)
#pragma unroll
        for (int nt = 0; nt < NTILES; ++nt) acc[mi][nt] = (f32x4){0.f, 0.f, 0.f, 0.f};
#pragma unroll
    for (int nt = 0; nt < NTILES; ++nt)
#pragma unroll
        for (int s = 0; s < 4; ++s) {
            short8 bf = *(const short8*)
                &Xt[(nt * 16 + l16) * 128 + (((4 * s + quad) ^ l16) * 8)];
            acc[0][nt] = mfma_bf16(af1[0][s], bf, acc[0][nt]);
            acc[1][nt] = mfma_bf16(af1[1][s], bf, acc[1][nt]);
        }

    // ---- BN1 + LeakyReLU ----
#pragma unroll
    for (int mi = 0; mi < 2; ++mi)
#pragma unroll
        for (int r = 0; r < 4; ++r) {
            int o = (wave * 2 + mi) * 16 + quad * 4 + r;
            float sc = jb.G1[o] * BNRS, bb = jb.B1[o];
#pragma unroll
            for (int nt = 0; nt < NTILES; ++nt) {
                float y = fmaf(acc[mi][nt][r], sc, bb);
                acc[mi][nt][r] = y > 0.f ? y : 0.1f * y;
            }
        }

    if (jb.nconv == 2) {
        // ---- mid -> Ct in B-operand swizzle ----
#pragma unroll
        for (int mi = 0; mi < 2; ++mi)
#pragma unroll
            for (int nt = 0; nt < NTILES; ++nt)
#pragma unroll
                for (int r = 0; r < 4; ++r) {
                    int o = (wave * 2 + mi) * 16 + quad * 4 + r;
                    int p = nt * 16 + l16;
                    Ct[p * 128 + (((o >> 3) ^ (p & 15)) * 8) + (o & 7)] =
                        f2bf(acc[mi][nt][r]);
                }
        __syncthreads();

        // ---- conv2 GEMM from Ct ----
#pragma unroll
        for (int mi = 0; mi < 2; ++mi)
#pragma unroll
            for (int nt = 0; nt < NTILES; ++nt) acc[mi][nt] = (f32x4){0.f, 0.f, 0.f, 0.f};
#pragma unroll
        for (int nt = 0; nt < NTILES; ++nt)
#pragma unroll
            for (int s = 0; s < 4; ++s) {
                short8 bf = *(const short8*)
                    &Ct[(nt * 16 + l16) * 128 + (((4 * s + quad) ^ l16) * 8)];
                acc[0][nt] = mfma_bf16(af2[0][s], bf, acc[0][nt]);
                acc[1][nt] = mfma_bf16(af2[1][s], bf, acc[1][nt]);
            }

        // ---- BN2 + LeakyReLU ----
#pragma unroll
        for (int mi = 0; mi < 2; ++mi)
#pragma unroll
            for (int r = 0; r < 4; ++r) {
                int o = (wave * 2 + mi) * 16 + quad * 4 + r;
                float sc = jb.G2[o] * BNRS, bb = jb.B2[o];
#pragma unroll
                for (int nt = 0; nt < NTILES; ++nt) {
                    float y = fmaf(acc[mi][nt][r], sc, bb);
                    acc[mi][nt][r] = y > 0.f ? y : 0.1f * y;
                }
            }
    }

    // ---- epilogue ----
    unsigned short* EP = (jb.nconv == 2) ? Xt : Ct;
    if (jb.out_mode == 0) {
        unsigned short* O = (unsigned short*)jb.out;
        float os = jb.oscale;
        if (jb.nconv != 2) __syncthreads();
#pragma unroll
        for (int mi = 0; mi < 2; ++mi)
#pragma unroll
            for (int nt = 0; nt < NTILES; ++nt)
#pragma unroll
                for (int r = 0; r < 4; ++r) {
                    int o = (wave * 2 + mi) * 16 + quad * 4 + r;
                    int p = nt * 16 + l16;
                    EP[p * 128 + (((o >> 3) ^ (p & 15)) * 8) + (o & 7)] =
                        f2bf(acc[mi][nt][r] * os);
                }
        __syncthreads();
#pragma unroll
        for (int i = 0; i < NTILES; ++i) {
            int idx = t + 256 * i;
            int p = idx >> 4, ch = idx & 15;
            uint4 v = *(const uint4*)&EP[p * 128 + ((ch ^ (p & 15)) * 8)];
            *(uint4*)&O[((size_t)b * HW_DIM + p0 + p) * C_DIM + ch * 8] = v;
        }
    } else if (jb.out_mode == 1) {
        // only used with NTILES=4 (V projection)
        unsigned short* O = (unsigned short*)jb.out;
        if (jb.nconv != 2) __syncthreads();
#pragma unroll
        for (int mi = 0; mi < 2; ++mi)
#pragma unroll
            for (int nt = 0; nt < NTILES; ++nt)
#pragma unroll
                for (int r = 0; r < 4; ++r) {
                    int o = (wave * 2 + mi) * 16 + quad * 4 + r;
                    int p = nt * 16 + l16;
                    EP[o * 64 + (((p >> 3) ^ (o & 7)) * 8) + (p & 7)] =
                        f2bf(acc[mi][nt][r]);
                }
        __syncthreads();
#pragma unroll
        for (int i = 0; i < 4; ++i) {          // all 1024 chunks (r14 fix)
            int idx = t + 256 * i;
            int o = idx >> 3, ch = idx & 7;
            uint4 v = *(const uint4*)&EP[o * 64 + ((ch ^ (o & 7)) * 8)];
            *(uint4*)&O[((size_t)b * C_DIM + o) * HW_DIM + p0 + ch * 8] = v;
        }
    } else {
        float* O = (float*)jb.out;
#pragma unroll
        for (int mi = 0; mi < 2; ++mi)
#pragma unroll
            for (int nt = 0; nt < NTILES; ++nt)
#pragma unroll
                for (int r = 0; r < 4; ++r) {
                    int o = (wave * 2 + mi) * 16 + quad * 4 + r;
                    size_t g = ((size_t)b * C_DIM + o) * HW_DIM + p0 + nt * 16 + l16;
                    O[g] = acc[mi][nt][r] + jb.resid[g];
                }
    }
}

// ---------------------------------------------------------------------------
// Flash attention (r22): double-buffered single-barrier pipeline.
//  - 512 blocks = 2b x 32qblk(192 rows, rt=3/wave) x 8ks; 256 thr;
//    __launch_bounds__(256,2) (cap 256 >= ~235 counted; r13 precedent for
//    this register shape ran spill-free).
//  - LDS 72 KB: TM[2][Kt 16K + Vt 16K] + Plds 8K -> exactly 2 blocks/CU.
//  - Per iteration: issue stage(it+1) into buf^1 FIRST, compute buf, then
//    ONE __syncthreads(). Its vmcnt(0) drain waits on loads that overlapped
//    the whole compute phase (~1500cy) instead of stalling cold (r16 paid
//    that stall 12x + a second barrier). Plds is wave-private -> no barrier
//    needed around the softmax round-trip.
//  - Buffer safety: buf^1's readers finished at the PREVIOUS barrier before
//    stage(it+1) issues; buf's loads drained at that same barrier.
// ---------------------------------------------------------------------------
template <int NSPLIT>
__global__ __launch_bounds__(256, 2)
void flash_attn(const unsigned short* __restrict__ Q,
                const unsigned short* __restrict__ K,
                const unsigned short* __restrict__ V,
                unsigned short* __restrict__ Pbase,
                float* __restrict__ Lbase)
{
    __shared__ __align__(16) unsigned short TM[2][16384];     // 64 KB dbuf
    __shared__ __align__(16) unsigned short Plds[4][16][64];  // 8 KB swizzled

    const int t    = threadIdx.x;
    const int wave = t >> 6;
    const int lane = t & 63;
    const int quad = lane >> 4;
    const int l16  = lane & 15;

    constexpr int KS_BITS = (NSPLIT == 8) ? 3 : 2;
    const int bid  = blockIdx.x;
    const int ks   = bid & (NSPLIT - 1);        // = XCD under round-robin
    const int fb   = (bid >> KS_BITS) & 1;
    const int qblk = bid >> (KS_BITS + 1);      // 0..31
    const int q0   = qblk * 192 + wave * 48;
    const int kbeg = ks * (HW_DIM / NSPLIT);

    unsigned short* __restrict__ Po = Pbase + (size_t)ks * (2 * HW_DIM * C_DIM);
    float* __restrict__ Lo          = Lbase + (size_t)ks * (2 * HW_DIM);

    const unsigned short* Qb = Q + (size_t)fb * HW_DIM * C_DIM;
    const unsigned short* Kb = K + (size_t)fb * HW_DIM * C_DIM;
    const unsigned short* Vb = V + (size_t)fb * C_DIM * HW_DIM;

    // Q fragments: 3 row-tiles x K=128
    short8 qf[3][4];
#pragma unroll
    for (int rt = 0; rt < 3; ++rt)
#pragma unroll
        for (int s = 0; s < 4; ++s)
            qf[rt][s] = *(const short8*)
                &Qb[(size_t)(q0 + rt * 16 + l16) * C_DIM + s * 32 + quad * 8];

    f32x4 O[3][8];
#pragma unroll
    for (int rt = 0; rt < 3; ++rt)
#pragma unroll
        for (int h = 0; h < 8; ++h) O[rt][h] = (f32x4){0.f, 0.f, 0.f, 0.f};
    float lsum[3][4] = {{0,0,0,0},{0,0,0,0},{0,0,0,0}};

    // Precomputed swizzled source offsets (ushort units) for staging.
    int koff[4], voff[4];
#pragma unroll
    for (int j = 0; j < 4; ++j) {
        int ci = t + 256 * j;
        int kr = ci >> 4, kc = ci & 15;
        koff[j] = kr * C_DIM + ((kc ^ (kr & 15)) << 3);
        int vr = ci >> 3, vc = ci & 7;
        voff[j] = vr * HW_DIM + ((vc ^ (vr & 7)) << 3);
    }

    const int NIT = (HW_DIM / NSPLIT) / 64;     // 12 (NSPLIT=8) / 24 (=4)

    // prologue: stage tile 0 into buf 0 (cold drain, paid once)
    {
        const unsigned short* Ksrc = Kb + (size_t)kbeg * C_DIM;
        const unsigned short* Vsrc = Vb + kbeg;
        unsigned short* Kt = TM[0];
        unsigned short* Vt = TM[0] + 8192;
#pragma unroll
        for (int j = 0; j < 4; ++j) {
            int ci = t + 256 * j;
            gload16(Ksrc + koff[j], &Kt[ci * 8]);
            gload16(Vsrc + voff[j], &Vt[ci * 8]);
        }
    }
    __syncthreads();

    int cur = 0;
    for (int it = 0; it < NIT; ++it) {
        // issue next tile's loads FIRST (land during compute below)
        if (it + 1 < NIT) {
            const int kb2 = kbeg + (it + 1) * 64;
            const unsigned short* Ksrc = Kb + (size_t)kb2 * C_DIM;
            const unsigned short* Vsrc = Vb + kb2;
            unsigned short* Kt2 = TM[cur ^ 1];
            unsigned short* Vt2 = TM[cur ^ 1] + 8192;
#pragma unroll
            for (int j = 0; j < 4; ++j) {
                int ci = t + 256 * j;
                gload16(Ksrc + koff[j], &Kt2[ci * 8]);
                gload16(Vsrc + voff[j], &Vt2[ci * 8]);
            }
        }

        unsigned short* Kt = TM[cur];
        unsigned short* Vt = TM[cur] + 8192;

        // ---- QK^T (joint over rt, shared kf reads) ----
        f32x4 S[3][4];
#pragma unroll
        for (int rt = 0; rt < 3; ++rt)
#pragma unroll
            for (int n = 0; n < 4; ++n) S[rt][n] = (f32x4){0.f, 0.f, 0.f, 0.f};
#pragma unroll
        for (int n = 0; n < 4; ++n)
#pragma unroll
            for (int s = 0; s < 4; ++s) {
                short8 kf = *(const short8*)
                    &Kt[(size_t)(n * 16 + l16) * 128 + (((4 * s + quad) ^ l16) * 8)];
                S[0][n] = mfma_bf16(qf[0][s], kf, S[0][n]);
                S[1][n] = mfma_bf16(qf[1][s], kf, S[1][n]);
                S[2][n] = mfma_bf16(qf[2][s], kf, S[2][n]);
            }

        // ---- exp2 -> Plds (wave-private, swizzled) -> pa fragments ----
        short8 pa[3][2];
#pragma unroll
        for (int rt = 0; rt < 3; ++rt) {
#pragma unroll
            for (int n = 0; n < 4; ++n)
#pragma unroll
                for (int r = 0; r < 4; ++r) {
                    float e = __builtin_amdgcn_exp2f(S[rt][n][r]);
                    lsum[rt][r] += e;
                    int row = quad * 4 + r;
                    Plds[wave][row][(((n * 2 + (l16 >> 3)) ^ (row & 7)) << 3) | (l16 & 7)] =
                        f2bf(e);
                }
            pa[rt][0] = *(const short8*)&Plds[wave][l16][((quad       ^ (l16 & 7)) << 3)];
            pa[rt][1] = *(const short8*)&Plds[wave][l16][(((4 + quad) ^ (l16 & 7)) << 3)];
        }

        // ---- PV (joint over rt, shared v reads) ----
        const int m = l16 & 7;
#pragma unroll
        for (int h = 0; h < 8; ++h) {
            short8 v0 = *(const short8*)&Vt[(size_t)(h * 16 + l16) * 64 + ((quad ^ m) * 8)];
            short8 v1 = *(const short8*)&Vt[(size_t)(h * 16 + l16) * 64 + (((quad + 4) ^ m) * 8)];
            O[0][h] = mfma_bf16(pa[0][0], v0, O[0][h]);
            O[0][h] = mfma_bf16(pa[0][1], v1, O[0][h]);
            O[1][h] = mfma_bf16(pa[1][0], v0, O[1][h]);
            O[1][h] = mfma_bf16(pa[1][1], v1, O[1][h]);
            O[2][h] = mfma_bf16(pa[2][0], v0, O[2][h]);
            O[2][h] = mfma_bf16(pa[2][1], v1, O[2][h]);
        }

        // ONE barrier: drains prefetch (overlapped with compute above) and
        // guards buf reuse for the next iteration.
        __syncthreads();
        cur ^= 1;
    }

    // ---- row-sum reduce across 16 cols ----
#pragma unroll
    for (int off = 1; off < 16; off <<= 1)
#pragma unroll
        for (int rt = 0; rt < 3; ++rt)
#pragma unroll
            for (int r = 0; r < 4; ++r)
                lsum[rt][r] += __shfl_xor(lsum[rt][r], off, 64);

    // ---- write P partial + L partial ----
#pragma unroll
    for (int rt = 0; rt < 3; ++rt)
#pragma unroll
        for (int r = 0; r < 4; ++r) {
            int lrow = wave * 48 + rt * 16 + quad * 4 + r;
            size_t row = (size_t)fb * HW_DIM + qblk * 192 + lrow;
            if (l16 == 0) Lo[row] = lsum[rt][r];
#pragma unroll
            for (int h = 0; h < 8; ++h)
                Po[row * C_DIM + h * 16 + l16] = f2bf(O[rt][h][r]);
        }
}

// ---------------------------------------------------------------------------
extern "C" void kernel_launch(void* const* d_in, const int* in_sizes, int n_in,
                              void* d_out, int out_size, void* d_ws, size_t ws_size,
                              hipStream_t stream)
{
    const float* query = (const float*)d_in[0];
    const float* key   = (const float*)d_in[1];
    const float* q_w1 = (const float*)d_in[2];
    const float* q_g1 = (const float*)d_in[3];
    const float* q_b1 = (const float*)d_in[4];
    const float* q_w2 = (const float*)d_in[5];
    const float* q_g2 = (const float*)d_in[6];
    const float* q_b2 = (const float*)d_in[7];
    const float* k_w1 = (const float*)d_in[8];
    const float* k_g1 = (const float*)d_in[9];
    const float* k_b1 = (const float*)d_in[10];
    const float* k_w2 = (const float*)d_in[11];
    const float* k_g2 = (const float*)d_in[12];
    const float* k_b2 = (const float*)d_in[13];
    const float* v_w  = (const float*)d_in[14];
    const float* v_g  = (const float*)d_in[15];
    const float* v_b  = (const float*)d_in[16];
    const float* o_w  = (const float*)d_in[17];
    const float* o_g  = (const float*)d_in[18];
    const float* o_b  = (const float*)d_in[19];

    // Workspace: [ P: nsplit x 3145728 ][ Qbf ][ Kbf ][ Vbf ][ L: nsplit x 49152 ]
    const size_t PPART = (size_t)2 * HW_DIM * C_DIM * 2;  // 3,145,728 B
    const size_t LPART = (size_t)2 * HW_DIM * 4;          // 49,152 B
    const int nsplit = (ws_size >= 11 * PPART + 8 * LPART) ? 8 : 4;

    char* ws = (char*)d_ws;
    unsigned short* Pbase = (unsigned short*)ws;
    unsigned short* Qbf = (unsigned short*)(ws + (size_t)nsplit * PPART);
    unsigned short* Kbf = (unsigned short*)(ws + (size_t)nsplit * PPART + PPART);
    unsigned short* Vbf = (unsigned short*)(ws + (size_t)nsplit * PPART + 2 * PPART);
    float*          Lbase = (float*)(ws + (size_t)nsplit * PPART + 3 * PPART);
    float* outp = (float*)d_out;

    const float qscale = 0.08838834764831845f * 1.44269504088896340f;

    auto kA  = conv_mfma<0, 4>;
    auto kC8 = conv_mfma<8, 2>;
    auto kC4 = conv_mfma<4, 2>;

    // Launch A: fused double-convs (r17-proven). z0: query->Qbf (scaled);
    // z1: key->Kbf; z2: key->v-conv->Vbf.
    {
        MJobs J{};
        J.j[0] = {query, nullptr, q_w1, q_g1, q_b1, q_w2, q_g2, q_b2,
                  (void*)Qbf, nullptr, qscale, 0, 0, 2};
        J.j[1] = {key,   nullptr, k_w1, k_g1, k_b1, k_w2, k_g2, k_b2,
                  (void*)Kbf, nullptr, 1.0f,   0, 0, 2};
        J.j[2] = {key,   nullptr, v_w,  v_g,  v_b,  nullptr, nullptr, nullptr,
                  (void*)Vbf, nullptr, 1.0f,   0, 1, 1};
        hipLaunchKernelGGL(kA, dim3(HW_DIM / 64, 2, 3), dim3(256), 0, stream, J);
    }

    // Flash: double-buffered pipeline, 512 blocks (2/CU exact), rt=3.
    if (nsplit == 8) {
        hipLaunchKernelGGL(HIP_KERNEL_NAME(flash_attn<8>),
                           dim3(2 * (HW_DIM / 192) * 8), dim3(256),
                           0, stream, Qbf, Kbf, Vbf, Pbase, Lbase);
    } else {
        hipLaunchKernelGGL(HIP_KERNEL_NAME(flash_attn<4>),
                           dim3(2 * (HW_DIM / 192) * 4), dim3(256),
                           0, stream, Qbf, Kbf, Vbf, Pbase, Lbase);
    }

    // Launch C: combine -> out-conv + residual. N=32/block, 384 blocks.
    {
        MJobs J{};
        J.j[0] = {Pbase, Lbase, o_w, o_g, o_b, nullptr, nullptr, nullptr,
                  (void*)outp, query, 1.0f, 2, 2, 1};
        J.j[1] = J.j[0];
        J.j[2] = J.j[0];
        if (nsplit == 8) {
            hipLaunchKernelGGL(kC8, dim3(HW_DIM / 32, 2, 1), dim3(256), 0, stream, J);
        } else {
            hipLaunchKernelGGL(kC4, dim3(HW_DIM / 32, 2, 1), dim3(256), 0, stream, J);
        }
    }
}

// Round 9
// 172.043 us; speedup vs baseline: 1.9168x; 1.0121x over previous
//
#include <hip/hip_runtime.h>

#define C_DIM 128
#define HW_DIM 6144

typedef __attribute__((ext_vector_type(8))) short short8;
typedef __attribute__((ext_vector_type(4))) float f32x4;

static __device__ __forceinline__ unsigned short f2bf(float x) {
    unsigned int u = __builtin_bit_cast(unsigned int, x);
    u = (u + 0x7FFFu + ((u >> 16) & 1u)) >> 16;
    return (unsigned short)u;
}
static __device__ __forceinline__ float bf2f(unsigned short u) {
    unsigned int x = ((unsigned int)u) << 16;
    return __builtin_bit_cast(float, x);
}
static __device__ __forceinline__ unsigned int pack2(float a, float b) {
    return (unsigned int)f2bf(a) | ((unsigned int)f2bf(b) << 16);
}
static __device__ __forceinline__ f32x4 mfma_bf16(short8 a, short8 b, f32x4 c) {
    return __builtin_amdgcn_mfma_f32_16x16x32_bf16(a, b, c, 0, 0, 0);
}
// async global->LDS, 16B per lane; LDS dest linear, global source pre-swizzled.
static __device__ __forceinline__ void gload16(const unsigned short* g,
                                               unsigned short* l) {
    __builtin_amdgcn_global_load_lds(
        (const __attribute__((address_space(1))) unsigned int*)g,
        (__attribute__((address_space(3))) unsigned int*)l, 16, 0, 0);
}
// MFMA A-fragment (bf16) directly from global fp32 W[o][c].
static __device__ __forceinline__ short8 wfrag(const float* Wrow) {
    float4 a = *(const float4*)Wrow;
    float4 b = *(const float4*)(Wrow + 4);
    unsigned int u[4] = {pack2(a.x, a.y), pack2(a.z, a.w),
                         pack2(b.x, b.y), pack2(b.z, b.w)};
    return *(const short8*)u;
}

// ---------------------------------------------------------------------------
// r23 launch A: QKV projections, key staged ONCE.
//   z=0: query -> conv1 -> conv2 -> Qbf (bf16 [b][pos][c], scaled)
//   z=1: key   -> {conv1 -> conv2 -> Kbf} AND {v-conv -> Vbf} off ONE X-tile
// Grid (96, 2, 2) = 384 blocks (was 576; key transpose-stage de-duplicated,
// -12.6 MB HBM). Staging uses packed b32 LDS writes (pairs (c,c+1) share a
// swizzle chunk since the XOR only involves c>>3; c&7 parity is preserved).
// ---------------------------------------------------------------------------
struct ProjArgs {
    const float* query; const float* key;
    const float* q_w1; const float* q_g1; const float* q_b1;
    const float* q_w2; const float* q_g2; const float* q_b2;
    const float* k_w1; const float* k_g1; const float* k_b1;
    const float* k_w2; const float* k_g2; const float* k_b2;
    const float* v_w;  const float* v_g;  const float* v_b;
    unsigned short* Qbf; unsigned short* Kbf; unsigned short* Vbf;
    float qscale;
};

__global__ __launch_bounds__(256)
void qkv_proj(ProjArgs A)
{
    __shared__ __align__(16) unsigned short Xt[64 * 128];   // 16 KB X tile
    __shared__ __align__(16) unsigned short Ct[64 * 128];   // 16 KB mid/epi

    const int t    = threadIdx.x;
    const int b    = blockIdx.y;
    const int p0   = blockIdx.x * 64;
    const int z    = blockIdx.z;            // 0: q-path, 1: k+v-path
    const int wave = t >> 6;
    const int lane = t & 63;
    const int quad = lane >> 4;
    const int l16  = lane & 15;
    const float BNRS = 0.99999500003749972f;  // 1/sqrt(1 + 1e-5)

    const float* Xg = (z == 0) ? A.query : A.key;
    const float* W1 = (z == 0) ? A.q_w1 : A.k_w1;
    const float* G1 = (z == 0) ? A.q_g1 : A.k_g1;
    const float* B1 = (z == 0) ? A.q_b1 : A.k_b1;
    const float* W2 = (z == 0) ? A.q_w2 : A.k_w2;
    const float* G2 = (z == 0) ? A.q_g2 : A.k_g2;
    const float* B2 = (z == 0) ? A.q_b2 : A.k_b2;

    // ---- W fragments direct from global ----
    short8 af1[2][4], af2[2][4];
#pragma unroll
    for (int mi = 0; mi < 2; ++mi) {
        int o = (wave * 2 + mi) * 16 + l16;
#pragma unroll
        for (int s = 0; s < 4; ++s) {
            af1[mi][s] = wfrag(W1 + o * C_DIM + s * 32 + quad * 8);
            af2[mi][s] = wfrag(W2 + o * C_DIM + s * 32 + quad * 8);
        }
    }

    // ---- stage X: fp32 [b][c][hw] -> bf16 Xt[p][chunk^(p&15)], b32 packed ----
    {
        const float* Xb = Xg + (size_t)b * C_DIM * HW_DIM;
#pragma unroll
        for (int i = 0; i < 4; ++i) {
            int w = i * 256 + t;              // 1024 work items
            int c = (w >> 4) * 2;             // even row
            int p = (w & 15) * 4;             // 4-col group
            float4 a4 = *(const float4*)&Xb[(size_t)c * HW_DIM + p0 + p];
            float4 b4 = *(const float4*)&Xb[(size_t)(c + 1) * HW_DIM + p0 + p];
            float av[4] = {a4.x, a4.y, a4.z, a4.w};
            float bv[4] = {b4.x, b4.y, b4.z, b4.w};
#pragma unroll
            for (int j = 0; j < 4; ++j) {
                int pp = p + j;
                int addr = pp * 128 + (((c >> 3) ^ (pp & 15)) * 8) + (c & 7);
                *(unsigned int*)&Xt[addr] = pack2(av[j], bv[j]);
            }
        }
    }
    __syncthreads();

    // ---- conv1 GEMM from Xt ----
    f32x4 acc[2][4];
#pragma unroll
    for (int mi = 0; mi < 2; ++mi)
#pragma unroll
        for (int nt = 0; nt < 4; ++nt) acc[mi][nt] = (f32x4){0.f, 0.f, 0.f, 0.f};
#pragma unroll
    for (int nt = 0; nt < 4; ++nt)
#pragma unroll
        for (int s = 0; s < 4; ++s) {
            short8 bf = *(const short8*)
                &Xt[(nt * 16 + l16) * 128 + (((4 * s + quad) ^ l16) * 8)];
            acc[0][nt] = mfma_bf16(af1[0][s], bf, acc[0][nt]);
            acc[1][nt] = mfma_bf16(af1[1][s], bf, acc[1][nt]);
        }
    // BN1 + LReLU
#pragma unroll
    for (int mi = 0; mi < 2; ++mi)
#pragma unroll
        for (int r = 0; r < 4; ++r) {
            int o = (wave * 2 + mi) * 16 + quad * 4 + r;
            float sc = G1[o] * BNRS, bb = B1[o];
#pragma unroll
            for (int nt = 0; nt < 4; ++nt) {
                float y = fmaf(acc[mi][nt][r], sc, bb);
                acc[mi][nt][r] = y > 0.f ? y : 0.1f * y;
            }
        }

    // ---- mid -> Ct (B-operand swizzle) ----
#pragma unroll
    for (int mi = 0; mi < 2; ++mi)
#pragma unroll
        for (int nt = 0; nt < 4; ++nt)
#pragma unroll
            for (int r = 0; r < 4; ++r) {
                int o = (wave * 2 + mi) * 16 + quad * 4 + r;
                int p = nt * 16 + l16;
                Ct[p * 128 + (((o >> 3) ^ (p & 15)) * 8) + (o & 7)] =
                    f2bf(acc[mi][nt][r]);
            }
    __syncthreads();

    // ---- conv2 GEMM from Ct ----
#pragma unroll
    for (int mi = 0; mi < 2; ++mi)
#pragma unroll
        for (int nt = 0; nt < 4; ++nt) acc[mi][nt] = (f32x4){0.f, 0.f, 0.f, 0.f};
#pragma unroll
    for (int nt = 0; nt < 4; ++nt)
#pragma unroll
        for (int s = 0; s < 4; ++s) {
            short8 bf = *(const short8*)
                &Ct[(nt * 16 + l16) * 128 + (((4 * s + quad) ^ l16) * 8)];
            acc[0][nt] = mfma_bf16(af2[0][s], bf, acc[0][nt]);
            acc[1][nt] = mfma_bf16(af2[1][s], bf, acc[1][nt]);
        }
    // BN2 + LReLU
#pragma unroll
    for (int mi = 0; mi < 2; ++mi)
#pragma unroll
        for (int r = 0; r < 4; ++r) {
            int o = (wave * 2 + mi) * 16 + quad * 4 + r;
            float sc = G2[o] * BNRS, bb = B2[o];
#pragma unroll
            for (int nt = 0; nt < 4; ++nt) {
                float y = fmaf(acc[mi][nt][r], sc, bb);
                acc[mi][nt][r] = y > 0.f ? y : 0.1f * y;
            }
        }

    if (z == 0) {
        // ---- q epilogue: bf16 [b][pos][c] * qscale via Xt (dead after conv1,
        //      safe: mid-sync ordered all conv1 reads before this) ----
        float os = A.qscale;
#pragma unroll
        for (int mi = 0; mi < 2; ++mi)
#pragma unroll
            for (int nt = 0; nt < 4; ++nt)
#pragma unroll
                for (int r = 0; r < 4; ++r) {
                    int o = (wave * 2 + mi) * 16 + quad * 4 + r;
                    int p = nt * 16 + l16;
                    Xt[p * 128 + (((o >> 3) ^ (p & 15)) * 8) + (o & 7)] =
                        f2bf(acc[mi][nt][r] * os);
                }
        __syncthreads();
#pragma unroll
        for (int i = 0; i < 4; ++i) {
            int idx = t + 256 * i;
            int p = idx >> 4, ch = idx & 15;
            uint4 v = *(const uint4*)&Xt[p * 128 + ((ch ^ (p & 15)) * 8)];
            *(uint4*)&A.Qbf[((size_t)b * HW_DIM + p0 + p) * C_DIM + ch * 8] = v;
        }
        return;
    }

    // ---- k epilogue via Ct (Xt must survive for v-conv) ----
    __syncthreads();   // all conv2 reads of Ct done
#pragma unroll
    for (int mi = 0; mi < 2; ++mi)
#pragma unroll
        for (int nt = 0; nt < 4; ++nt)
#pragma unroll
            for (int r = 0; r < 4; ++r) {
                int o = (wave * 2 + mi) * 16 + quad * 4 + r;
                int p = nt * 16 + l16;
                Ct[p * 128 + (((o >> 3) ^ (p & 15)) * 8) + (o & 7)] =
                    f2bf(acc[mi][nt][r]);
            }
    __syncthreads();
#pragma unroll
    for (int i = 0; i < 4; ++i) {
        int idx = t + 256 * i;
        int p = idx >> 4, ch = idx & 15;
        uint4 v = *(const uint4*)&Ct[p * 128 + ((ch ^ (p & 15)) * 8)];
        *(uint4*)&A.Kbf[((size_t)b * HW_DIM + p0 + p) * C_DIM + ch * 8] = v;
    }

    // ---- v-conv from the SAME Xt ----
    short8 afv[2][4];
#pragma unroll
    for (int mi = 0; mi < 2; ++mi) {
        int o = (wave * 2 + mi) * 16 + l16;
#pragma unroll
        for (int s = 0; s < 4; ++s)
            afv[mi][s] = wfrag(A.v_w + o * C_DIM + s * 32 + quad * 8);
    }
#pragma unroll
    for (int mi = 0; mi < 2; ++mi)
#pragma unroll
        for (int nt = 0; nt < 4; ++nt) acc[mi][nt] = (f32x4){0.f, 0.f, 0.f, 0.f};
#pragma unroll
    for (int nt = 0; nt < 4; ++nt)
#pragma unroll
        for (int s = 0; s < 4; ++s) {
            short8 bf = *(const short8*)
                &Xt[(nt * 16 + l16) * 128 + (((4 * s + quad) ^ l16) * 8)];
            acc[0][nt] = mfma_bf16(afv[0][s], bf, acc[0][nt]);
            acc[1][nt] = mfma_bf16(afv[1][s], bf, acc[1][nt]);
        }
#pragma unroll
    for (int mi = 0; mi < 2; ++mi)
#pragma unroll
        for (int r = 0; r < 4; ++r) {
            int o = (wave * 2 + mi) * 16 + quad * 4 + r;
            float sc = A.v_g[o] * BNRS, bb = A.v_b[o];
#pragma unroll
            for (int nt = 0; nt < 4; ++nt) {
                float y = fmaf(acc[mi][nt][r], sc, bb);
                acc[mi][nt][r] = y > 0.f ? y : 0.1f * y;
            }
        }

    // ---- v epilogue: bf16 [b][c][pos] via Ct ----
    __syncthreads();   // Kbf-store reads of Ct done
#pragma unroll
    for (int mi = 0; mi < 2; ++mi)
#pragma unroll
        for (int nt = 0; nt < 4; ++nt)
#pragma unroll
            for (int r = 0; r < 4; ++r) {
                int o = (wave * 2 + mi) * 16 + quad * 4 + r;
                int p = nt * 16 + l16;
                Ct[o * 64 + (((p >> 3) ^ (o & 7)) * 8) + (p & 7)] =
                    f2bf(acc[mi][nt][r]);
            }
    __syncthreads();
#pragma unroll
    for (int i = 0; i < 4; ++i) {              // all 1024 chunks (r14 fix)
        int idx = t + 256 * i;
        int o = idx >> 3, ch = idx & 7;
        uint4 v = *(const uint4*)&Ct[o * 64 + ((ch ^ (o & 7)) * 8)];
        *(uint4*)&A.Vbf[((size_t)b * C_DIM + o) * HW_DIM + p0 + ch * 8] = v;
    }
}

// ---------------------------------------------------------------------------
// Flash attention (r22 compute, r23 INTERLEAVED partial layout):
//   P[row][part][128] bf16, L[row][part] f32 — write-index change only
//   (same 256B-per-row coalescing; combine reads become sequential).
// ---------------------------------------------------------------------------
template <int NSPLIT>
__global__ __launch_bounds__(256, 2)
void flash_attn(const unsigned short* __restrict__ Q,
                const unsigned short* __restrict__ K,
                const unsigned short* __restrict__ V,
                unsigned short* __restrict__ Pint,
                float* __restrict__ Lint)
{
    __shared__ __align__(16) unsigned short TM[2][16384];     // 64 KB dbuf
    __shared__ __align__(16) unsigned short Plds[4][16][64];  // 8 KB swizzled

    const int t    = threadIdx.x;
    const int wave = t >> 6;
    const int lane = t & 63;
    const int quad = lane >> 4;
    const int l16  = lane & 15;

    constexpr int KS_BITS = (NSPLIT == 8) ? 3 : 2;
    const int bid  = blockIdx.x;
    const int ks   = bid & (NSPLIT - 1);        // = XCD under round-robin
    const int fb   = (bid >> KS_BITS) & 1;
    const int qblk = bid >> (KS_BITS + 1);      // 0..31
    const int q0   = qblk * 192 + wave * 48;
    const int kbeg = ks * (HW_DIM / NSPLIT);

    const unsigned short* Qb = Q + (size_t)fb * HW_DIM * C_DIM;
    const unsigned short* Kb = K + (size_t)fb * HW_DIM * C_DIM;
    const unsigned short* Vb = V + (size_t)fb * C_DIM * HW_DIM;

    short8 qf[3][4];
#pragma unroll
    for (int rt = 0; rt < 3; ++rt)
#pragma unroll
        for (int s = 0; s < 4; ++s)
            qf[rt][s] = *(const short8*)
                &Qb[(size_t)(q0 + rt * 16 + l16) * C_DIM + s * 32 + quad * 8];

    f32x4 O[3][8];
#pragma unroll
    for (int rt = 0; rt < 3; ++rt)
#pragma unroll
        for (int h = 0; h < 8; ++h) O[rt][h] = (f32x4){0.f, 0.f, 0.f, 0.f};
    float lsum[3][4] = {{0,0,0,0},{0,0,0,0},{0,0,0,0}};

    int koff[4], voff[4];
#pragma unroll
    for (int j = 0; j < 4; ++j) {
        int ci = t + 256 * j;
        int kr = ci >> 4, kc = ci & 15;
        koff[j] = kr * C_DIM + ((kc ^ (kr & 15)) << 3);
        int vr = ci >> 3, vc = ci & 7;
        voff[j] = vr * HW_DIM + ((vc ^ (vr & 7)) << 3);
    }

    const int NIT = (HW_DIM / NSPLIT) / 64;

    // prologue: stage tile 0 into buf 0
    {
        const unsigned short* Ksrc = Kb + (size_t)kbeg * C_DIM;
        const unsigned short* Vsrc = Vb + kbeg;
        unsigned short* Kt = TM[0];
        unsigned short* Vt = TM[0] + 8192;
#pragma unroll
        for (int j = 0; j < 4; ++j) {
            int ci = t + 256 * j;
            gload16(Ksrc + koff[j], &Kt[ci * 8]);
            gload16(Vsrc + voff[j], &Vt[ci * 8]);
        }
    }
    __syncthreads();

    int cur = 0;
    for (int it = 0; it < NIT; ++it) {
        if (it + 1 < NIT) {
            const int kb2 = kbeg + (it + 1) * 64;
            const unsigned short* Ksrc = Kb + (size_t)kb2 * C_DIM;
            const unsigned short* Vsrc = Vb + kb2;
            unsigned short* Kt2 = TM[cur ^ 1];
            unsigned short* Vt2 = TM[cur ^ 1] + 8192;
#pragma unroll
            for (int j = 0; j < 4; ++j) {
                int ci = t + 256 * j;
                gload16(Ksrc + koff[j], &Kt2[ci * 8]);
                gload16(Vsrc + voff[j], &Vt2[ci * 8]);
            }
        }

        unsigned short* Kt = TM[cur];
        unsigned short* Vt = TM[cur] + 8192;

        f32x4 S[3][4];
#pragma unroll
        for (int rt = 0; rt < 3; ++rt)
#pragma unroll
            for (int n = 0; n < 4; ++n) S[rt][n] = (f32x4){0.f, 0.f, 0.f, 0.f};
#pragma unroll
        for (int n = 0; n < 4; ++n)
#pragma unroll
            for (int s = 0; s < 4; ++s) {
                short8 kf = *(const short8*)
                    &Kt[(size_t)(n * 16 + l16) * 128 + (((4 * s + quad) ^ l16) * 8)];
                S[0][n] = mfma_bf16(qf[0][s], kf, S[0][n]);
                S[1][n] = mfma_bf16(qf[1][s], kf, S[1][n]);
                S[2][n] = mfma_bf16(qf[2][s], kf, S[2][n]);
            }

        short8 pa[3][2];
#pragma unroll
        for (int rt = 0; rt < 3; ++rt) {
#pragma unroll
            for (int n = 0; n < 4; ++n)
#pragma unroll
                for (int r = 0; r < 4; ++r) {
                    float e = __builtin_amdgcn_exp2f(S[rt][n][r]);
                    lsum[rt][r] += e;
                    int row = quad * 4 + r;
                    Plds[wave][row][(((n * 2 + (l16 >> 3)) ^ (row & 7)) << 3) | (l16 & 7)] =
                        f2bf(e);
                }
            pa[rt][0] = *(const short8*)&Plds[wave][l16][((quad       ^ (l16 & 7)) << 3)];
            pa[rt][1] = *(const short8*)&Plds[wave][l16][(((4 + quad) ^ (l16 & 7)) << 3)];
        }

        const int m = l16 & 7;
#pragma unroll
        for (int h = 0; h < 8; ++h) {
            short8 v0 = *(const short8*)&Vt[(size_t)(h * 16 + l16) * 64 + ((quad ^ m) * 8)];
            short8 v1 = *(const short8*)&Vt[(size_t)(h * 16 + l16) * 64 + (((quad + 4) ^ m) * 8)];
            O[0][h] = mfma_bf16(pa[0][0], v0, O[0][h]);
            O[0][h] = mfma_bf16(pa[0][1], v1, O[0][h]);
            O[1][h] = mfma_bf16(pa[1][0], v0, O[1][h]);
            O[1][h] = mfma_bf16(pa[1][1], v1, O[1][h]);
            O[2][h] = mfma_bf16(pa[2][0], v0, O[2][h]);
            O[2][h] = mfma_bf16(pa[2][1], v1, O[2][h]);
        }

        __syncthreads();
        cur ^= 1;
    }

#pragma unroll
    for (int off = 1; off < 16; off <<= 1)
#pragma unroll
        for (int rt = 0; rt < 3; ++rt)
#pragma unroll
            for (int r = 0; r < 4; ++r)
                lsum[rt][r] += __shfl_xor(lsum[rt][r], off, 64);

    // ---- write P/L partials (interleaved layout) ----
#pragma unroll
    for (int rt = 0; rt < 3; ++rt)
#pragma unroll
        for (int r = 0; r < 4; ++r) {
            int lrow = wave * 48 + rt * 16 + quad * 4 + r;
            size_t row = (size_t)fb * HW_DIM + qblk * 192 + lrow;
            if (l16 == 0) Lint[row * NSPLIT + ks] = lsum[rt][r];
#pragma unroll
            for (int h = 0; h < 8; ++h)
                Pint[row * (NSPLIT * C_DIM) + ks * C_DIM + h * 16 + l16] =
                    f2bf(O[rt][h][r]);
        }
}

// ---------------------------------------------------------------------------
// r23 launch C: combine (sequential-stream reads from interleaved P/L)
// + out-conv + residual. N=32/block, 384 blocks.
// ---------------------------------------------------------------------------
template <int NPARTS>
__global__ __launch_bounds__(256)
void combine_out(const unsigned short* __restrict__ Pint,
                 const float* __restrict__ Lint,
                 const float* __restrict__ OW,
                 const float* __restrict__ OG,
                 const float* __restrict__ OB,
                 const float* __restrict__ RESID,
                 float* __restrict__ OUT)
{
    __shared__ __align__(16) unsigned short Xt[32 * 128];   // 8 KB
    __shared__ float invl[32];

    const int t    = threadIdx.x;
    const int b    = blockIdx.y;
    const int p0   = blockIdx.x * 32;
    const int wave = t >> 6;
    const int lane = t & 63;
    const int quad = lane >> 4;
    const int l16  = lane & 15;
    const float BNRS = 0.99999500003749972f;

    short8 af[2][4];
#pragma unroll
    for (int mi = 0; mi < 2; ++mi) {
        int o = (wave * 2 + mi) * 16 + l16;
#pragma unroll
        for (int s = 0; s < 4; ++s)
            af[mi][s] = wfrag(OW + o * C_DIM + s * 32 + quad * 8);
    }

    if (t < 32) {
        size_t row = (size_t)b * HW_DIM + p0 + t;
        float s = 0.f;
#pragma unroll
        for (int pr = 0; pr < NPARTS; ++pr)
            s += Lint[row * NPARTS + pr];
        invl[t] = 1.0f / s;
    }
    __syncthreads();

#pragma unroll
    for (int i = 0; i < 2; ++i) {
        int idx = t + 256 * i;
        int p = idx >> 4, ch = idx & 15;
        size_t row = (size_t)b * HW_DIM + p0 + p;
        size_t base = row * (NPARTS * C_DIM) + ch * 8;
        float acc8[8] = {0.f, 0.f, 0.f, 0.f, 0.f, 0.f, 0.f, 0.f};
#pragma unroll
        for (int pr = 0; pr < NPARTS; ++pr) {
            uint4 a = *(const uint4*)&Pint[base + (size_t)pr * C_DIM];
            const unsigned int* ap = (const unsigned int*)&a;
#pragma unroll
            for (int j = 0; j < 4; ++j) {
                acc8[2 * j]     += bf2f((unsigned short)(ap[j] & 0xFFFF));
                acc8[2 * j + 1] += bf2f((unsigned short)(ap[j] >> 16));
            }
        }
        float s = invl[p];
        unsigned int w[4];
#pragma unroll
        for (int j = 0; j < 4; ++j)
            w[j] = pack2(acc8[2 * j] * s, acc8[2 * j + 1] * s);
        *(uint4*)&Xt[p * 128 + ((ch ^ (p & 15)) * 8)] = *(uint4*)w;
    }
    __syncthreads();

    f32x4 acc[2][2];
#pragma unroll
    for (int mi = 0; mi < 2; ++mi)
#pragma unroll
        for (int nt = 0; nt < 2; ++nt) acc[mi][nt] = (f32x4){0.f, 0.f, 0.f, 0.f};
#pragma unroll
    for (int nt = 0; nt < 2; ++nt)
#pragma unroll
        for (int s = 0; s < 4; ++s) {
            short8 bf = *(const short8*)
                &Xt[(nt * 16 + l16) * 128 + (((4 * s + quad) ^ l16) * 8)];
            acc[0][nt] = mfma_bf16(af[0][s], bf, acc[0][nt]);
            acc[1][nt] = mfma_bf16(af[1][s], bf, acc[1][nt]);
        }

#pragma unroll
    for (int mi = 0; mi < 2; ++mi)
#pragma unroll
        for (int r = 0; r < 4; ++r) {
            int o = (wave * 2 + mi) * 16 + quad * 4 + r;
            float sc = OG[o] * BNRS, bb = OB[o];
#pragma unroll
            for (int nt = 0; nt < 2; ++nt) {
                float y = fmaf(acc[mi][nt][r], sc, bb);
                y = y > 0.f ? y : 0.1f * y;
                size_t g = ((size_t)b * C_DIM + o) * HW_DIM + p0 + nt * 16 + l16;
                OUT[g] = y + RESID[g];
            }
        }
}

// ---------------------------------------------------------------------------
extern "C" void kernel_launch(void* const* d_in, const int* in_sizes, int n_in,
                              void* d_out, int out_size, void* d_ws, size_t ws_size,
                              hipStream_t stream)
{
    // Workspace: [ Pint: nsplit*3145728 B ][ Qbf ][ Kbf ][ Vbf ][ Lint: nsplit*49152 B ]
    const size_t PPART = (size_t)2 * HW_DIM * C_DIM * 2;  // 3,145,728 B
    const size_t LPART = (size_t)2 * HW_DIM * 4;          // 49,152 B
    const int nsplit = (ws_size >= 11 * PPART + 8 * LPART) ? 8 : 4;

    char* ws = (char*)d_ws;
    unsigned short* Pint = (unsigned short*)ws;
    unsigned short* Qbf = (unsigned short*)(ws + (size_t)nsplit * PPART);
    unsigned short* Kbf = (unsigned short*)(ws + (size_t)nsplit * PPART + PPART);
    unsigned short* Vbf = (unsigned short*)(ws + (size_t)nsplit * PPART + 2 * PPART);
    float*          Lint = (float*)(ws + (size_t)nsplit * PPART + 3 * PPART);
    float* outp = (float*)d_out;

    // Launch A: QKV projections, key staged once. Grid (96,2,2)=384 blocks.
    {
        ProjArgs pa;
        pa.query = (const float*)d_in[0];
        pa.key   = (const float*)d_in[1];
        pa.q_w1 = (const float*)d_in[2];  pa.q_g1 = (const float*)d_in[3];
        pa.q_b1 = (const float*)d_in[4];
        pa.q_w2 = (const float*)d_in[5];  pa.q_g2 = (const float*)d_in[6];
        pa.q_b2 = (const float*)d_in[7];
        pa.k_w1 = (const float*)d_in[8];  pa.k_g1 = (const float*)d_in[9];
        pa.k_b1 = (const float*)d_in[10];
        pa.k_w2 = (const float*)d_in[11]; pa.k_g2 = (const float*)d_in[12];
        pa.k_b2 = (const float*)d_in[13];
        pa.v_w  = (const float*)d_in[14]; pa.v_g  = (const float*)d_in[15];
        pa.v_b  = (const float*)d_in[16];
        pa.Qbf = Qbf; pa.Kbf = Kbf; pa.Vbf = Vbf;
        pa.qscale = 0.08838834764831845f * 1.44269504088896340f;
        hipLaunchKernelGGL(qkv_proj, dim3(HW_DIM / 64, 2, 2), dim3(256),
                           0, stream, pa);
    }

    // Flash: r22 pipeline, interleaved P/L writes. 512 blocks (2/CU), rt=3.
    if (nsplit == 8) {
        hipLaunchKernelGGL(HIP_KERNEL_NAME(flash_attn<8>),
                           dim3(2 * (HW_DIM / 192) * 8), dim3(256),
                           0, stream, Qbf, Kbf, Vbf, Pint, Lint);
    } else {
        hipLaunchKernelGGL(HIP_KERNEL_NAME(flash_attn<4>),
                           dim3(2 * (HW_DIM / 192) * 4), dim3(256),
                           0, stream, Qbf, Kbf, Vbf, Pint, Lint);
    }

    // Launch C: combine (streaming reads) + out-conv + residual. 384 blocks.
    {
        const float* o_w = (const float*)d_in[17];
        const float* o_g = (const float*)d_in[18];
        const float* o_b = (const float*)d_in[19];
        if (nsplit == 8) {
            hipLaunchKernelGGL(HIP_KERNEL_NAME(combine_out<8>),
                               dim3(HW_DIM / 32, 2), dim3(256), 0, stream,
                               Pint, Lint, o_w, o_g, o_b,
                               (const float*)d_in[0], outp);
        } else {
            hipLaunchKernelGGL(HIP_KERNEL_NAME(combine_out<4>),
                               dim3(HW_DIM / 32, 2), dim3(256), 0, stream,
                               Pint, Lint, o_w, o_g, o_b,
                               (const float*)d_in[0], outp);
        }
    }
}

// Round 10
// 168.301 us; speedup vs baseline: 1.9595x; 1.0222x over previous
//
#include <hip/hip_runtime.h>

#define C_DIM 128
#define HW_DIM 6144

typedef __attribute__((ext_vector_type(8))) short short8;
typedef __attribute__((ext_vector_type(4))) float f32x4;

static __device__ __forceinline__ unsigned short f2bf(float x) {
    unsigned int u = __builtin_bit_cast(unsigned int, x);
    u = (u + 0x7FFFu + ((u >> 16) & 1u)) >> 16;
    return (unsigned short)u;
}
static __device__ __forceinline__ float bf2f(unsigned short u) {
    unsigned int x = ((unsigned int)u) << 16;
    return __builtin_bit_cast(float, x);
}
static __device__ __forceinline__ unsigned int pack2(float a, float b) {
    return (unsigned int)f2bf(a) | ((unsigned int)f2bf(b) << 16);
}
static __device__ __forceinline__ f32x4 mfma_bf16(short8 a, short8 b, f32x4 c) {
    return __builtin_amdgcn_mfma_f32_16x16x32_bf16(a, b, c, 0, 0, 0);
}
// async global->LDS, 16B per lane; LDS dest linear, global source pre-swizzled.
static __device__ __forceinline__ void gload16(const unsigned short* g,
                                               unsigned short* l) {
    __builtin_amdgcn_global_load_lds(
        (const __attribute__((address_space(1))) unsigned int*)g,
        (__attribute__((address_space(3))) unsigned int*)l, 16, 0, 0);
}
// MFMA A-fragment (bf16) directly from global fp32 W[o][c].
static __device__ __forceinline__ short8 wfrag(const float* Wrow) {
    float4 a = *(const float4*)Wrow;
    float4 b = *(const float4*)(Wrow + 4);
    unsigned int u[4] = {pack2(a.x, a.y), pack2(a.z, a.w),
                         pack2(b.x, b.y), pack2(b.z, b.w)};
    return *(const short8*)u;
}

// ---------------------------------------------------------------------------
// r24 launch A: QKV projections (r23 structure) + T14 async-stage split.
// The r23 staging loop consumed each load pair (pack2 + LDS write) before
// issuing the next -> ~2 loads in flight/thread -> ~1 TB/s effective on the
// 25 MB fp32 input stream at 6 waves/CU. Now: issue ALL 8 X float4 loads
// into registers FIRST, then the 32 W-fragment L2 loads (fill the HBM
// latency window), then convert + LDS-write. Same addresses, same
// arithmetic -> bit-identical output.
// ---------------------------------------------------------------------------
struct ProjArgs {
    const float* query; const float* key;
    const float* q_w1; const float* q_g1; const float* q_b1;
    const float* q_w2; const float* q_g2; const float* q_b2;
    const float* k_w1; const float* k_g1; const float* k_b1;
    const float* k_w2; const float* k_g2; const float* k_b2;
    const float* v_w;  const float* v_g;  const float* v_b;
    unsigned short* Qbf; unsigned short* Kbf; unsigned short* Vbf;
    float qscale;
};

__global__ __launch_bounds__(256)
void qkv_proj(ProjArgs A)
{
    __shared__ __align__(16) unsigned short Xt[64 * 128];   // 16 KB X tile
    __shared__ __align__(16) unsigned short Ct[64 * 128];   // 16 KB mid/epi

    const int t    = threadIdx.x;
    const int b    = blockIdx.y;
    const int p0   = blockIdx.x * 64;
    const int z    = blockIdx.z;            // 0: q-path, 1: k+v-path
    const int wave = t >> 6;
    const int lane = t & 63;
    const int quad = lane >> 4;
    const int l16  = lane & 15;
    const float BNRS = 0.99999500003749972f;  // 1/sqrt(1 + 1e-5)

    const float* Xg = (z == 0) ? A.query : A.key;
    const float* W1 = (z == 0) ? A.q_w1 : A.k_w1;
    const float* G1 = (z == 0) ? A.q_g1 : A.k_g1;
    const float* B1 = (z == 0) ? A.q_b1 : A.k_b1;
    const float* W2 = (z == 0) ? A.q_w2 : A.k_w2;
    const float* G2 = (z == 0) ? A.q_g2 : A.k_g2;
    const float* B2 = (z == 0) ? A.q_b2 : A.k_b2;

    // ---- T14 step 1: issue ALL X loads (HBM) into registers ----
    const float* Xb = Xg + (size_t)b * C_DIM * HW_DIM;
    float4 xa[4], xb4[4];
#pragma unroll
    for (int i = 0; i < 4; ++i) {
        int w = i * 256 + t;              // 1024 work items
        int c = (w >> 4) * 2;             // even row
        int p = (w & 15) * 4;             // 4-col group
        xa[i]  = *(const float4*)&Xb[(size_t)c * HW_DIM + p0 + p];
        xb4[i] = *(const float4*)&Xb[(size_t)(c + 1) * HW_DIM + p0 + p];
    }

    // ---- T14 step 2: W fragments (L2) — latency fills the HBM window ----
    short8 af1[2][4], af2[2][4];
#pragma unroll
    for (int mi = 0; mi < 2; ++mi) {
        int o = (wave * 2 + mi) * 16 + l16;
#pragma unroll
        for (int s = 0; s < 4; ++s) {
            af1[mi][s] = wfrag(W1 + o * C_DIM + s * 32 + quad * 8);
            af2[mi][s] = wfrag(W2 + o * C_DIM + s * 32 + quad * 8);
        }
    }

    // ---- T14 step 3: convert + LDS write (loads have landed by now) ----
#pragma unroll
    for (int i = 0; i < 4; ++i) {
        int w = i * 256 + t;
        int c = (w >> 4) * 2;
        int p = (w & 15) * 4;
        float av[4] = {xa[i].x, xa[i].y, xa[i].z, xa[i].w};
        float bv[4] = {xb4[i].x, xb4[i].y, xb4[i].z, xb4[i].w};
#pragma unroll
        for (int j = 0; j < 4; ++j) {
            int pp = p + j;
            int addr = pp * 128 + (((c >> 3) ^ (pp & 15)) * 8) + (c & 7);
            *(unsigned int*)&Xt[addr] = pack2(av[j], bv[j]);
        }
    }
    __syncthreads();

    // ---- conv1 GEMM from Xt ----
    f32x4 acc[2][4];
#pragma unroll
    for (int mi = 0; mi < 2; ++mi)
#pragma unroll
        for (int nt = 0; nt < 4; ++nt) acc[mi][nt] = (f32x4){0.f, 0.f, 0.f, 0.f};
#pragma unroll
    for (int nt = 0; nt < 4; ++nt)
#pragma unroll
        for (int s = 0; s < 4; ++s) {
            short8 bf = *(const short8*)
                &Xt[(nt * 16 + l16) * 128 + (((4 * s + quad) ^ l16) * 8)];
            acc[0][nt] = mfma_bf16(af1[0][s], bf, acc[0][nt]);
            acc[1][nt] = mfma_bf16(af1[1][s], bf, acc[1][nt]);
        }
    // BN1 + LReLU
#pragma unroll
    for (int mi = 0; mi < 2; ++mi)
#pragma unroll
        for (int r = 0; r < 4; ++r) {
            int o = (wave * 2 + mi) * 16 + quad * 4 + r;
            float sc = G1[o] * BNRS, bb = B1[o];
#pragma unroll
            for (int nt = 0; nt < 4; ++nt) {
                float y = fmaf(acc[mi][nt][r], sc, bb);
                acc[mi][nt][r] = y > 0.f ? y : 0.1f * y;
            }
        }

    // ---- mid -> Ct (B-operand swizzle) ----
#pragma unroll
    for (int mi = 0; mi < 2; ++mi)
#pragma unroll
        for (int nt = 0; nt < 4; ++nt)
#pragma unroll
            for (int r = 0; r < 4; ++r) {
                int o = (wave * 2 + mi) * 16 + quad * 4 + r;
                int p = nt * 16 + l16;
                Ct[p * 128 + (((o >> 3) ^ (p & 15)) * 8) + (o & 7)] =
                    f2bf(acc[mi][nt][r]);
            }
    __syncthreads();

    // ---- conv2 GEMM from Ct ----
#pragma unroll
    for (int mi = 0; mi < 2; ++mi)
#pragma unroll
        for (int nt = 0; nt < 4; ++nt) acc[mi][nt] = (f32x4){0.f, 0.f, 0.f, 0.f};
#pragma unroll
    for (int nt = 0; nt < 4; ++nt)
#pragma unroll
        for (int s = 0; s < 4; ++s) {
            short8 bf = *(const short8*)
                &Ct[(nt * 16 + l16) * 128 + (((4 * s + quad) ^ l16) * 8)];
            acc[0][nt] = mfma_bf16(af2[0][s], bf, acc[0][nt]);
            acc[1][nt] = mfma_bf16(af2[1][s], bf, acc[1][nt]);
        }
    // BN2 + LReLU
#pragma unroll
    for (int mi = 0; mi < 2; ++mi)
#pragma unroll
        for (int r = 0; r < 4; ++r) {
            int o = (wave * 2 + mi) * 16 + quad * 4 + r;
            float sc = G2[o] * BNRS, bb = B2[o];
#pragma unroll
            for (int nt = 0; nt < 4; ++nt) {
                float y = fmaf(acc[mi][nt][r], sc, bb);
                acc[mi][nt][r] = y > 0.f ? y : 0.1f * y;
            }
        }

    if (z == 0) {
        // ---- q epilogue: bf16 [b][pos][c] * qscale via Xt ----
        float os = A.qscale;
#pragma unroll
        for (int mi = 0; mi < 2; ++mi)
#pragma unroll
            for (int nt = 0; nt < 4; ++nt)
#pragma unroll
                for (int r = 0; r < 4; ++r) {
                    int o = (wave * 2 + mi) * 16 + quad * 4 + r;
                    int p = nt * 16 + l16;
                    Xt[p * 128 + (((o >> 3) ^ (p & 15)) * 8) + (o & 7)] =
                        f2bf(acc[mi][nt][r] * os);
                }
        __syncthreads();
#pragma unroll
        for (int i = 0; i < 4; ++i) {
            int idx = t + 256 * i;
            int p = idx >> 4, ch = idx & 15;
            uint4 v = *(const uint4*)&Xt[p * 128 + ((ch ^ (p & 15)) * 8)];
            *(uint4*)&A.Qbf[((size_t)b * HW_DIM + p0 + p) * C_DIM + ch * 8] = v;
        }
        return;
    }

    // ---- k epilogue via Ct (Xt must survive for v-conv) ----
    __syncthreads();   // all conv2 reads of Ct done
#pragma unroll
    for (int mi = 0; mi < 2; ++mi)
#pragma unroll
        for (int nt = 0; nt < 4; ++nt)
#pragma unroll
            for (int r = 0; r < 4; ++r) {
                int o = (wave * 2 + mi) * 16 + quad * 4 + r;
                int p = nt * 16 + l16;
                Ct[p * 128 + (((o >> 3) ^ (p & 15)) * 8) + (o & 7)] =
                    f2bf(acc[mi][nt][r]);
            }
    __syncthreads();
#pragma unroll
    for (int i = 0; i < 4; ++i) {
        int idx = t + 256 * i;
        int p = idx >> 4, ch = idx & 15;
        uint4 v = *(const uint4*)&Ct[p * 128 + ((ch ^ (p & 15)) * 8)];
        *(uint4*)&A.Kbf[((size_t)b * HW_DIM + p0 + p) * C_DIM + ch * 8] = v;
    }

    // ---- v-conv from the SAME Xt ----
    short8 afv[2][4];
#pragma unroll
    for (int mi = 0; mi < 2; ++mi) {
        int o = (wave * 2 + mi) * 16 + l16;
#pragma unroll
        for (int s = 0; s < 4; ++s)
            afv[mi][s] = wfrag(A.v_w + o * C_DIM + s * 32 + quad * 8);
    }
#pragma unroll
    for (int mi = 0; mi < 2; ++mi)
#pragma unroll
        for (int nt = 0; nt < 4; ++nt) acc[mi][nt] = (f32x4){0.f, 0.f, 0.f, 0.f};
#pragma unroll
    for (int nt = 0; nt < 4; ++nt)
#pragma unroll
        for (int s = 0; s < 4; ++s) {
            short8 bf = *(const short8*)
                &Xt[(nt * 16 + l16) * 128 + (((4 * s + quad) ^ l16) * 8)];
            acc[0][nt] = mfma_bf16(afv[0][s], bf, acc[0][nt]);
            acc[1][nt] = mfma_bf16(afv[1][s], bf, acc[1][nt]);
        }
#pragma unroll
    for (int mi = 0; mi < 2; ++mi)
#pragma unroll
        for (int r = 0; r < 4; ++r) {
            int o = (wave * 2 + mi) * 16 + quad * 4 + r;
            float sc = A.v_g[o] * BNRS, bb = A.v_b[o];
#pragma unroll
            for (int nt = 0; nt < 4; ++nt) {
                float y = fmaf(acc[mi][nt][r], sc, bb);
                acc[mi][nt][r] = y > 0.f ? y : 0.1f * y;
            }
        }

    // ---- v epilogue: bf16 [b][c][pos] via Ct ----
    __syncthreads();   // Kbf-store reads of Ct done
#pragma unroll
    for (int mi = 0; mi < 2; ++mi)
#pragma unroll
        for (int nt = 0; nt < 4; ++nt)
#pragma unroll
            for (int r = 0; r < 4; ++r) {
                int o = (wave * 2 + mi) * 16 + quad * 4 + r;
                int p = nt * 16 + l16;
                Ct[o * 64 + (((p >> 3) ^ (o & 7)) * 8) + (p & 7)] =
                    f2bf(acc[mi][nt][r]);
            }
    __syncthreads();
#pragma unroll
    for (int i = 0; i < 4; ++i) {              // all 1024 chunks (r14 fix)
        int idx = t + 256 * i;
        int o = idx >> 3, ch = idx & 7;
        uint4 v = *(const uint4*)&Ct[o * 64 + ((ch ^ (o & 7)) * 8)];
        *(uint4*)&A.Vbf[((size_t)b * C_DIM + o) * HW_DIM + p0 + ch * 8] = v;
    }
}

// ---------------------------------------------------------------------------
// Flash attention (r23 EXACT — passing at 54.2 µs; untouched).
// ---------------------------------------------------------------------------
template <int NSPLIT>
__global__ __launch_bounds__(256, 2)
void flash_attn(const unsigned short* __restrict__ Q,
                const unsigned short* __restrict__ K,
                const unsigned short* __restrict__ V,
                unsigned short* __restrict__ Pint,
                float* __restrict__ Lint)
{
    __shared__ __align__(16) unsigned short TM[2][16384];     // 64 KB dbuf
    __shared__ __align__(16) unsigned short Plds[4][16][64];  // 8 KB swizzled

    const int t    = threadIdx.x;
    const int wave = t >> 6;
    const int lane = t & 63;
    const int quad = lane >> 4;
    const int l16  = lane & 15;

    constexpr int KS_BITS = (NSPLIT == 8) ? 3 : 2;
    const int bid  = blockIdx.x;
    const int ks   = bid & (NSPLIT - 1);        // = XCD under round-robin
    const int fb   = (bid >> KS_BITS) & 1;
    const int qblk = bid >> (KS_BITS + 1);      // 0..31
    const int q0   = qblk * 192 + wave * 48;
    const int kbeg = ks * (HW_DIM / NSPLIT);

    const unsigned short* Qb = Q + (size_t)fb * HW_DIM * C_DIM;
    const unsigned short* Kb = K + (size_t)fb * HW_DIM * C_DIM;
    const unsigned short* Vb = V + (size_t)fb * C_DIM * HW_DIM;

    short8 qf[3][4];
#pragma unroll
    for (int rt = 0; rt < 3; ++rt)
#pragma unroll
        for (int s = 0; s < 4; ++s)
            qf[rt][s] = *(const short8*)
                &Qb[(size_t)(q0 + rt * 16 + l16) * C_DIM + s * 32 + quad * 8];

    f32x4 O[3][8];
#pragma unroll
    for (int rt = 0; rt < 3; ++rt)
#pragma unroll
        for (int h = 0; h < 8; ++h) O[rt][h] = (f32x4){0.f, 0.f, 0.f, 0.f};
    float lsum[3][4] = {{0,0,0,0},{0,0,0,0},{0,0,0,0}};

    int koff[4], voff[4];
#pragma unroll
    for (int j = 0; j < 4; ++j) {
        int ci = t + 256 * j;
        int kr = ci >> 4, kc = ci & 15;
        koff[j] = kr * C_DIM + ((kc ^ (kr & 15)) << 3);
        int vr = ci >> 3, vc = ci & 7;
        voff[j] = vr * HW_DIM + ((vc ^ (vr & 7)) << 3);
    }

    const int NIT = (HW_DIM / NSPLIT) / 64;

    // prologue: stage tile 0 into buf 0
    {
        const unsigned short* Ksrc = Kb + (size_t)kbeg * C_DIM;
        const unsigned short* Vsrc = Vb + kbeg;
        unsigned short* Kt = TM[0];
        unsigned short* Vt = TM[0] + 8192;
#pragma unroll
        for (int j = 0; j < 4; ++j) {
            int ci = t + 256 * j;
            gload16(Ksrc + koff[j], &Kt[ci * 8]);
            gload16(Vsrc + voff[j], &Vt[ci * 8]);
        }
    }
    __syncthreads();

    int cur = 0;
    for (int it = 0; it < NIT; ++it) {
        if (it + 1 < NIT) {
            const int kb2 = kbeg + (it + 1) * 64;
            const unsigned short* Ksrc = Kb + (size_t)kb2 * C_DIM;
            const unsigned short* Vsrc = Vb + kb2;
            unsigned short* Kt2 = TM[cur ^ 1];
            unsigned short* Vt2 = TM[cur ^ 1] + 8192;
#pragma unroll
            for (int j = 0; j < 4; ++j) {
                int ci = t + 256 * j;
                gload16(Ksrc + koff[j], &Kt2[ci * 8]);
                gload16(Vsrc + voff[j], &Vt2[ci * 8]);
            }
        }

        unsigned short* Kt = TM[cur];
        unsigned short* Vt = TM[cur] + 8192;

        f32x4 S[3][4];
#pragma unroll
        for (int rt = 0; rt < 3; ++rt)
#pragma unroll
            for (int n = 0; n < 4; ++n) S[rt][n] = (f32x4){0.f, 0.f, 0.f, 0.f};
#pragma unroll
        for (int n = 0; n < 4; ++n)
#pragma unroll
            for (int s = 0; s < 4; ++s) {
                short8 kf = *(const short8*)
                    &Kt[(size_t)(n * 16 + l16) * 128 + (((4 * s + quad) ^ l16) * 8)];
                S[0][n] = mfma_bf16(qf[0][s], kf, S[0][n]);
                S[1][n] = mfma_bf16(qf[1][s], kf, S[1][n]);
                S[2][n] = mfma_bf16(qf[2][s], kf, S[2][n]);
            }

        short8 pa[3][2];
#pragma unroll
        for (int rt = 0; rt < 3; ++rt) {
#pragma unroll
            for (int n = 0; n < 4; ++n)
#pragma unroll
                for (int r = 0; r < 4; ++r) {
                    float e = __builtin_amdgcn_exp2f(S[rt][n][r]);
                    lsum[rt][r] += e;
                    int row = quad * 4 + r;
                    Plds[wave][row][(((n * 2 + (l16 >> 3)) ^ (row & 7)) << 3) | (l16 & 7)] =
                        f2bf(e);
                }
            pa[rt][0] = *(const short8*)&Plds[wave][l16][((quad       ^ (l16 & 7)) << 3)];
            pa[rt][1] = *(const short8*)&Plds[wave][l16][(((4 + quad) ^ (l16 & 7)) << 3)];
        }

        const int m = l16 & 7;
#pragma unroll
        for (int h = 0; h < 8; ++h) {
            short8 v0 = *(const short8*)&Vt[(size_t)(h * 16 + l16) * 64 + ((quad ^ m) * 8)];
            short8 v1 = *(const short8*)&Vt[(size_t)(h * 16 + l16) * 64 + (((quad + 4) ^ m) * 8)];
            O[0][h] = mfma_bf16(pa[0][0], v0, O[0][h]);
            O[0][h] = mfma_bf16(pa[0][1], v1, O[0][h]);
            O[1][h] = mfma_bf16(pa[1][0], v0, O[1][h]);
            O[1][h] = mfma_bf16(pa[1][1], v1, O[1][h]);
            O[2][h] = mfma_bf16(pa[2][0], v0, O[2][h]);
            O[2][h] = mfma_bf16(pa[2][1], v1, O[2][h]);
        }

        __syncthreads();
        cur ^= 1;
    }

#pragma unroll
    for (int off = 1; off < 16; off <<= 1)
#pragma unroll
        for (int rt = 0; rt < 3; ++rt)
#pragma unroll
            for (int r = 0; r < 4; ++r)
                lsum[rt][r] += __shfl_xor(lsum[rt][r], off, 64);

    // ---- write P/L partials (interleaved layout) ----
#pragma unroll
    for (int rt = 0; rt < 3; ++rt)
#pragma unroll
        for (int r = 0; r < 4; ++r) {
            int lrow = wave * 48 + rt * 16 + quad * 4 + r;
            size_t row = (size_t)fb * HW_DIM + qblk * 192 + lrow;
            if (l16 == 0) Lint[row * NSPLIT + ks] = lsum[rt][r];
#pragma unroll
            for (int h = 0; h < 8; ++h)
                Pint[row * (NSPLIT * C_DIM) + ks * C_DIM + h * 16 + l16] =
                    f2bf(O[rt][h][r]);
        }
}

// ---------------------------------------------------------------------------
// r24 launch C: combine + out-conv + residual, T14 load batching.
// ALL 16 partial uint4 loads (both row-iterations) issue into registers
// before any accumulation; W fragments issue after them (L2 fills window).
// ---------------------------------------------------------------------------
template <int NPARTS>
__global__ __launch_bounds__(256)
void combine_out(const unsigned short* __restrict__ Pint,
                 const float* __restrict__ Lint,
                 const float* __restrict__ OW,
                 const float* __restrict__ OG,
                 const float* __restrict__ OB,
                 const float* __restrict__ RESID,
                 float* __restrict__ OUT)
{
    __shared__ __align__(16) unsigned short Xt[32 * 128];   // 8 KB
    __shared__ float invl[32];

    const int t    = threadIdx.x;
    const int b    = blockIdx.y;
    const int p0   = blockIdx.x * 32;
    const int wave = t >> 6;
    const int lane = t & 63;
    const int quad = lane >> 4;
    const int l16  = lane & 15;
    const float BNRS = 0.99999500003749972f;

    // ---- T14: issue ALL partial loads first ----
    uint4 pv[2][NPARTS];
#pragma unroll
    for (int i = 0; i < 2; ++i) {
        int idx = t + 256 * i;
        int p = idx >> 4, ch = idx & 15;
        size_t row = (size_t)b * HW_DIM + p0 + p;
        size_t base = row * (NPARTS * C_DIM) + ch * 8;
#pragma unroll
        for (int pr = 0; pr < NPARTS; ++pr)
            pv[i][pr] = *(const uint4*)&Pint[base + (size_t)pr * C_DIM];
    }

    // ---- W fragments (L2) while partials stream ----
    short8 af[2][4];
#pragma unroll
    for (int mi = 0; mi < 2; ++mi) {
        int o = (wave * 2 + mi) * 16 + l16;
#pragma unroll
        for (int s = 0; s < 4; ++s)
            af[mi][s] = wfrag(OW + o * C_DIM + s * 32 + quad * 8);
    }

    if (t < 32) {
        size_t row = (size_t)b * HW_DIM + p0 + t;
        float s = 0.f;
#pragma unroll
        for (int pr = 0; pr < NPARTS; ++pr)
            s += Lint[row * NPARTS + pr];
        invl[t] = 1.0f / s;
    }
    __syncthreads();

    // ---- accumulate + normalize -> Xt ----
#pragma unroll
    for (int i = 0; i < 2; ++i) {
        int idx = t + 256 * i;
        int p = idx >> 4, ch = idx & 15;
        float acc8[8] = {0.f, 0.f, 0.f, 0.f, 0.f, 0.f, 0.f, 0.f};
#pragma unroll
        for (int pr = 0; pr < NPARTS; ++pr) {
            const unsigned int* ap = (const unsigned int*)&pv[i][pr];
#pragma unroll
            for (int j = 0; j < 4; ++j) {
                acc8[2 * j]     += bf2f((unsigned short)(ap[j] & 0xFFFF));
                acc8[2 * j + 1] += bf2f((unsigned short)(ap[j] >> 16));
            }
        }
        float s = invl[p];
        unsigned int w[4];
#pragma unroll
        for (int j = 0; j < 4; ++j)
            w[j] = pack2(acc8[2 * j] * s, acc8[2 * j + 1] * s);
        *(uint4*)&Xt[p * 128 + ((ch ^ (p & 15)) * 8)] = *(uint4*)w;
    }
    __syncthreads();

    f32x4 acc[2][2];
#pragma unroll
    for (int mi = 0; mi < 2; ++mi)
#pragma unroll
        for (int nt = 0; nt < 2; ++nt) acc[mi][nt] = (f32x4){0.f, 0.f, 0.f, 0.f};
#pragma unroll
    for (int nt = 0; nt < 2; ++nt)
#pragma unroll
        for (int s = 0; s < 4; ++s) {
            short8 bf = *(const short8*)
                &Xt[(nt * 16 + l16) * 128 + (((4 * s + quad) ^ l16) * 8)];
            acc[0][nt] = mfma_bf16(af[0][s], bf, acc[0][nt]);
            acc[1][nt] = mfma_bf16(af[1][s], bf, acc[1][nt]);
        }

#pragma unroll
    for (int mi = 0; mi < 2; ++mi)
#pragma unroll
        for (int r = 0; r < 4; ++r) {
            int o = (wave * 2 + mi) * 16 + quad * 4 + r;
            float sc = OG[o] * BNRS, bb = OB[o];
#pragma unroll
            for (int nt = 0; nt < 2; ++nt) {
                float y = fmaf(acc[mi][nt][r], sc, bb);
                y = y > 0.f ? y : 0.1f * y;
                size_t g = ((size_t)b * C_DIM + o) * HW_DIM + p0 + nt * 16 + l16;
                OUT[g] = y + RESID[g];
            }
        }
}

// ---------------------------------------------------------------------------
extern "C" void kernel_launch(void* const* d_in, const int* in_sizes, int n_in,
                              void* d_out, int out_size, void* d_ws, size_t ws_size,
                              hipStream_t stream)
{
    // Workspace: [ Pint: nsplit*3145728 B ][ Qbf ][ Kbf ][ Vbf ][ Lint: nsplit*49152 B ]
    const size_t PPART = (size_t)2 * HW_DIM * C_DIM * 2;  // 3,145,728 B
    const size_t LPART = (size_t)2 * HW_DIM * 4;          // 49,152 B
    const int nsplit = (ws_size >= 11 * PPART + 8 * LPART) ? 8 : 4;

    char* ws = (char*)d_ws;
    unsigned short* Pint = (unsigned short*)ws;
    unsigned short* Qbf = (unsigned short*)(ws + (size_t)nsplit * PPART);
    unsigned short* Kbf = (unsigned short*)(ws + (size_t)nsplit * PPART + PPART);
    unsigned short* Vbf = (unsigned short*)(ws + (size_t)nsplit * PPART + 2 * PPART);
    float*          Lint = (float*)(ws + (size_t)nsplit * PPART + 3 * PPART);
    float* outp = (float*)d_out;

    // Launch A: QKV projections, key staged once. Grid (96,2,2)=384 blocks.
    {
        ProjArgs pa;
        pa.query = (const float*)d_in[0];
        pa.key   = (const float*)d_in[1];
        pa.q_w1 = (const float*)d_in[2];  pa.q_g1 = (const float*)d_in[3];
        pa.q_b1 = (const float*)d_in[4];
        pa.q_w2 = (const float*)d_in[5];  pa.q_g2 = (const float*)d_in[6];
        pa.q_b2 = (const float*)d_in[7];
        pa.k_w1 = (const float*)d_in[8];  pa.k_g1 = (const float*)d_in[9];
        pa.k_b1 = (const float*)d_in[10];
        pa.k_w2 = (const float*)d_in[11]; pa.k_g2 = (const float*)d_in[12];
        pa.k_b2 = (const float*)d_in[13];
        pa.v_w  = (const float*)d_in[14]; pa.v_g  = (const float*)d_in[15];
        pa.v_b  = (const float*)d_in[16];
        pa.Qbf = Qbf; pa.Kbf = Kbf; pa.Vbf = Vbf;
        pa.qscale = 0.08838834764831845f * 1.44269504088896340f;
        hipLaunchKernelGGL(qkv_proj, dim3(HW_DIM / 64, 2, 2), dim3(256),
                           0, stream, pa);
    }

    // Flash: r23 pipeline (unchanged). 512 blocks (2/CU), rt=3.
    if (nsplit == 8) {
        hipLaunchKernelGGL(HIP_KERNEL_NAME(flash_attn<8>),
                           dim3(2 * (HW_DIM / 192) * 8), dim3(256),
                           0, stream, Qbf, Kbf, Vbf, Pint, Lint);
    } else {
        hipLaunchKernelGGL(HIP_KERNEL_NAME(flash_attn<4>),
                           dim3(2 * (HW_DIM / 192) * 4), dim3(256),
                           0, stream, Qbf, Kbf, Vbf, Pint, Lint);
    }

    // Launch C: combine (batched streaming reads) + out-conv + residual.
    {
        const float* o_w = (const float*)d_in[17];
        const float* o_g = (const float*)d_in[18];
        const float* o_b = (const float*)d_in[19];
        if (nsplit == 8) {
            hipLaunchKernelGGL(HIP_KERNEL_NAME(combine_out<8>),
                               dim3(HW_DIM / 32, 2), dim3(256), 0, stream,
                               Pint, Lint, o_w, o_g, o_b,
                               (const float*)d_in[0], outp);
        } else {
            hipLaunchKernelGGL(HIP_KERNEL_NAME(combine_out<4>),
                               dim3(HW_DIM / 32, 2), dim3(256), 0, stream,
                               Pint, Lint, o_w, o_g, o_b,
                               (const float*)d_in[0], outp);
        }
    }
}